// Round 9
// baseline (400.276 us; speedup 1.0000x reference)
//
#include <hip/hip_runtime.h>
#include <hip/hip_bf16.h>
#include <math.h>

#define BB 4
#define LL 4096
#define DM 256
#define DI 512
#define DS 16
#define NOUTK 128
#define LN_EPS 1e-5f
#define NC 128
#define CLEN (LL/NC)
#define BL (BB*LL)

typedef __attribute__((ext_vector_type(8))) short short8;
typedef __attribute__((ext_vector_type(4))) float f32x4;

__device__ __forceinline__ ushort f2bf(float f) {
    union { float f; unsigned u; } v; v.f = f;
    unsigned r = (v.u + 0x7FFF + ((v.u >> 16) & 1)) >> 16;
    return (ushort)r;
}
__device__ __forceinline__ float bf2f(ushort u) {
    union { unsigned u; float f; } v; v.u = ((unsigned)u) << 16;
    return v.f;
}

// ---------------- fused weight prep + encoder ------------------------------
// Blocks [0, PREP_BLOCKS): weight prep (inw/opw cast, xpw48 cast).
// Blocks [PREP_BLOCKS, ...): encoder rows.
#define PREP_N1 (2*1024*256)
#define PREP_N2 (2*256*512)
#define PREP_N3 (2*64*512)     /* xpw rows 0..47 cast to bf16, padded to 64 */
#define PREP_BLOCKS ((PREP_N1 + PREP_N2 + PREP_N3) / 256)
#define ENC_BLOCKS (BL / 4)
__global__ __launch_bounds__(256) void prep_enc_kernel(
    const float* __restrict__ inw, const float* __restrict__ opw,
    const float* __restrict__ xpw,
    ushort* __restrict__ inw_bf, ushort* __restrict__ opw_bf,
    ushort* __restrict__ xpw48_bf,
    const float* __restrict__ x, const float* __restrict__ encw,
    const float* __restrict__ encb, ushort* __restrict__ hbf)
{
    int tid = threadIdx.x;
    if (blockIdx.x < PREP_BLOCKS) {
        int i = blockIdx.x * 256 + tid;
        if (i < PREP_N1) {
            inw_bf[i] = f2bf(inw[i]);
            return;
        }
        int j = i - PREP_N1;
        if (j < PREP_N2) {
            opw_bf[j] = f2bf(opw[j]);
            return;
        }
        int m = j - PREP_N2;
        if (m >= PREP_N3) return;
        int l = m / (64 * 512);
        int rem = m - l * 64 * 512;
        int row = rem >> 9, k = rem & 511;
        float v = (row < 48) ? xpw[(size_t)l * 48 * 512 + row * 512 + k] : 0.f;
        xpw48_bf[m] = f2bf(v);
        return;
    }
    // ---- encoder branch ----
    __shared__ float sw[256 * 33];
    __shared__ float sx[4][32];
    for (int i = tid; i < 256 * 8; i += 256) {
        float4 v = ((const float4*)encw)[i];
        int r = i >> 3, c = (i & 7) * 4;
        sw[r * 33 + c + 0] = v.x; sw[r * 33 + c + 1] = v.y;
        sw[r * 33 + c + 2] = v.z; sw[r * 33 + c + 3] = v.w;
    }
    int row0 = (blockIdx.x - PREP_BLOCKS) * 4;
    if (tid < 32) {
        for (int rr = 0; rr < 4; ++rr)
            sx[rr][tid] = x[(size_t)(row0 + rr) * 32 + tid];
    }
    __syncthreads();
    float bb = encb[tid];
    #pragma unroll
    for (int rr = 0; rr < 4; ++rr) {
        float acc = bb;
        #pragma unroll
        for (int k = 0; k < 32; ++k)
            acc = fmaf(sx[rr][k], sw[tid * 33 + k], acc);
        hbf[(size_t)(row0 + rr) * DM + tid] = f2bf(acc);
    }
}

// ---------------- bf16 MFMA GEMM: C = epi(A @ W^T) -------------------------
// Tile 64(M) x 128(N), 4 waves of 32x64, single-buffered 24 KB LDS
// (m97-style 2-barrier k-loop; latency hidden by co-resident blocks).
// FROZEN CONFIG. Post-mortems:
//  R3: explicit LDS double-buffer (48 KB) -> -31 us (residency 6->3).
//  R5: forced launch_bounds(256,6) -> spill, flat despite traffic cuts.
//  R7: LDS-free direct fragment loads -> 2x SLOWER (each wave load touches
//      16 cache lines; LDS staging IS the coalescing transform here).
// EPI: 0 plain bf16 out; 2 residual bf16 read-modify-write on Cbf.
template<int EPI>
__global__ __launch_bounds__(256, 4) void mfma_gemm(
    const ushort* __restrict__ A, int lda,
    const ushort* __restrict__ W,
    ushort* Cbf, int ldcbf,
    int K)
{
    __shared__ ushort As[64 * 64];
    __shared__ ushort Ws[128 * 64];
    const int tid = threadIdx.x;

    // XCD-aware bijective swizzle (nwg % 8 == 0 for all our launches)
    int nwg = gridDim.x * gridDim.y;
    int wlin = blockIdx.y * gridDim.x + blockIdx.x;
    int gx = blockIdx.x, gy = blockIdx.y;
    if ((nwg & 7) == 0) {
        int q = nwg >> 3;
        int s = (wlin & 7) * q + (wlin >> 3);
        gx = s % gridDim.x;
        gy = s / gridDim.x;
    }
    const int bm = gy * 64;
    const int bn = gx * 128;
    const int wid = tid >> 6, lane = tid & 63;
    const int wrow = (wid >> 1) * 32, wcol = (wid & 1) * 64;
    const int sr = tid >> 3;
    const int sc = tid & 7;

    f32x4 acc[2][4];
    #pragma unroll
    for (int mi = 0; mi < 2; ++mi)
        #pragma unroll
        for (int ni = 0; ni < 4; ++ni)
            acc[mi][ni] = (f32x4){0.f, 0.f, 0.f, 0.f};

    const int nk = K >> 6;          // 4 (K=256) or 8 (K=512)
    for (int t = 0; t < nk; ++t) {
        const int k0 = t << 6;
        #pragma unroll
        for (int it = 0; it < 2; ++it) {
            int r = it * 32 + sr;
            int csrc = sc ^ (r & 7);
            __builtin_amdgcn_global_load_lds(
                (const __attribute__((address_space(1))) unsigned int*)
                    (A + (size_t)(bm + r) * lda + k0 + csrc * 8),
                (__attribute__((address_space(3))) unsigned int*)
                    (As + r * 64 + sc * 8), 16, 0, 0);
        }
        #pragma unroll
        for (int it = 0; it < 4; ++it) {
            int r = it * 32 + sr;
            int csrc = sc ^ (r & 7);
            __builtin_amdgcn_global_load_lds(
                (const __attribute__((address_space(1))) unsigned int*)
                    (W + (size_t)(bn + r) * K + k0 + csrc * 8),
                (__attribute__((address_space(3))) unsigned int*)
                    (Ws + r * 64 + sc * 8), 16, 0, 0);
        }
        __syncthreads();
        #pragma unroll
        for (int kk = 0; kk < 2; ++kk) {
            short8 af[2], bfr[4];
            #pragma unroll
            for (int mi = 0; mi < 2; ++mi) {
                int r = wrow + mi * 16 + (lane & 15);
                int c = (lane >> 4) + kk * 4;
                af[mi] = *(const short8*)(As + r * 64 + ((c ^ (r & 7)) << 3));
            }
            #pragma unroll
            for (int ni = 0; ni < 4; ++ni) {
                int r = wcol + ni * 16 + (lane & 15);
                int c = (lane >> 4) + kk * 4;
                bfr[ni] = *(const short8*)(Ws + r * 64 + ((c ^ (r & 7)) << 3));
            }
            #pragma unroll
            for (int mi = 0; mi < 2; ++mi)
                #pragma unroll
                for (int ni = 0; ni < 4; ++ni)
                    acc[mi][ni] = __builtin_amdgcn_mfma_f32_16x16x32_bf16(
                        af[mi], bfr[ni], acc[mi][ni], 0, 0, 0);
        }
        __syncthreads();
    }

    #pragma unroll
    for (int mi = 0; mi < 2; ++mi)
        #pragma unroll
        for (int ni = 0; ni < 4; ++ni) {
            int col = bn + wcol + ni * 16 + (lane & 15);
            #pragma unroll
            for (int r = 0; r < 4; ++r) {
                int row = bm + wrow + mi * 16 + (lane >> 4) * 4 + r;
                float v = acc[mi][ni][r];
                if (EPI == 2) {
                    size_t o = (size_t)row * ldcbf + col;
                    float vv = v + bf2f(Cbf[o]);
                    Cbf[o] = f2bf(vv);
                } else {
                    Cbf[(size_t)row * ldcbf + col] = f2bf(v);
                }
            }
        }
}

// ---------------- skinny xproj GEMM: [r16 | B | C] = xi @ xpw48^T ----------
// M=64 x N=64 tile (N=48 useful), 4 waves of 16x64, 16 KB LDS, same
// verified k-loop/fragment pattern as mfma_gemm. Grid (1, BL/64) = 256
// blocks = 1/CU; single round -> per-block latency paid once (~2-3 us).
// Rank-16 factorization: dt is finished by dt_combine (K=16, f32).
__global__ __launch_bounds__(256, 4) void mfma_gemm48(
    const ushort* __restrict__ A,      // xi_bf, lda = 512
    const ushort* __restrict__ W,      // xpw48_bf layer base: 64 x 512
    float* __restrict__ r16,           // BL x 16 f32
    float* __restrict__ bc)            // BL x 32 f32
{
    __shared__ ushort As[64 * 64];
    __shared__ ushort Ws[64 * 64];
    const int tid = threadIdx.x;

    int nwg = gridDim.y;               // 256
    int wlin = blockIdx.y;
    int gy = wlin;
    if ((nwg & 7) == 0) {
        int q = nwg >> 3;
        gy = (wlin & 7) * q + (wlin >> 3);
    }
    const int bm = gy * 64;
    const int wid = tid >> 6, lane = tid & 63;
    const int wrow = wid * 16;
    const int sr = tid >> 3;
    const int sc = tid & 7;

    f32x4 acc[4];
    #pragma unroll
    for (int ni = 0; ni < 4; ++ni)
        acc[ni] = (f32x4){0.f, 0.f, 0.f, 0.f};

    for (int t = 0; t < 8; ++t) {      // K = 512
        const int k0 = t << 6;
        #pragma unroll
        for (int it = 0; it < 2; ++it) {
            int r = it * 32 + sr;
            int csrc = sc ^ (r & 7);
            __builtin_amdgcn_global_load_lds(
                (const __attribute__((address_space(1))) unsigned int*)
                    (A + (size_t)(bm + r) * DI + k0 + csrc * 8),
                (__attribute__((address_space(3))) unsigned int*)
                    (As + r * 64 + sc * 8), 16, 0, 0);
        }
        #pragma unroll
        for (int it = 0; it < 2; ++it) {
            int r = it * 32 + sr;
            int csrc = sc ^ (r & 7);
            __builtin_amdgcn_global_load_lds(
                (const __attribute__((address_space(1))) unsigned int*)
                    (W + (size_t)r * DI + k0 + csrc * 8),
                (__attribute__((address_space(3))) unsigned int*)
                    (Ws + r * 64 + sc * 8), 16, 0, 0);
        }
        __syncthreads();
        #pragma unroll
        for (int kk = 0; kk < 2; ++kk) {
            int c = (lane >> 4) + kk * 4;
            int ra = wrow + (lane & 15);
            short8 af = *(const short8*)(As + ra * 64 + ((c ^ (ra & 7)) << 3));
            #pragma unroll
            for (int ni = 0; ni < 4; ++ni) {
                int rb = ni * 16 + (lane & 15);
                short8 bfr = *(const short8*)(Ws + rb * 64 + ((c ^ (rb & 7)) << 3));
                acc[ni] = __builtin_amdgcn_mfma_f32_16x16x32_bf16(
                    af, bfr, acc[ni], 0, 0, 0);
            }
        }
        __syncthreads();
    }

    #pragma unroll
    for (int ni = 0; ni < 3; ++ni) {   // cols 48-63 are zero-pad, skip ni=3
        int col = ni * 16 + (lane & 15);
        #pragma unroll
        for (int r = 0; r < 4; ++r) {
            int row = bm + wrow + (lane >> 4) * 4 + r;
            float v = acc[ni][r];
            if (col < 16) r16[(size_t)row * 16 + col] = v;
            else          bc[(size_t)row * 32 + (col - 16)] = v;
        }
    }
}

// ---------------- dt finish: dt = softplus(r16 @ dtw^T + dtb), bf16 --------
__global__ __launch_bounds__(256) void dt_combine_kernel(
    const float* __restrict__ r16, const float* __restrict__ dtw,
    const float* __restrict__ dtb, ushort* __restrict__ dt_bf)
{
    int idx = blockIdx.x * 256 + threadIdx.x;   // over BL*128
    int n0 = (idx & 127) * 4;
    int row = idx >> 7;
    const float* rp = r16 + (size_t)row * 16;
    float4 ra = *(const float4*)(rp + 0);
    float4 rb = *(const float4*)(rp + 4);
    float4 rc = *(const float4*)(rp + 8);
    float4 rd = *(const float4*)(rp + 12);
    ushort4 o;
    #pragma unroll
    for (int j = 0; j < 4; ++j) {
        const float* w = dtw + (size_t)(n0 + j) * 16;
        float4 wa = *(const float4*)(w + 0);
        float4 wb = *(const float4*)(w + 4);
        float4 wc = *(const float4*)(w + 8);
        float4 wd = *(const float4*)(w + 12);
        float acc = dtb[n0 + j];
        acc = fmaf(ra.x, wa.x, acc); acc = fmaf(ra.y, wa.y, acc);
        acc = fmaf(ra.z, wa.z, acc); acc = fmaf(ra.w, wa.w, acc);
        acc = fmaf(rb.x, wb.x, acc); acc = fmaf(rb.y, wb.y, acc);
        acc = fmaf(rb.z, wb.z, acc); acc = fmaf(rb.w, wb.w, acc);
        acc = fmaf(rc.x, wc.x, acc); acc = fmaf(rc.y, wc.y, acc);
        acc = fmaf(rc.z, wc.z, acc); acc = fmaf(rc.w, wc.w, acc);
        acc = fmaf(rd.x, wd.x, acc); acc = fmaf(rd.y, wd.y, acc);
        acc = fmaf(rd.z, wd.z, acc); acc = fmaf(rd.w, wd.w, acc);
        float sp = fmaxf(acc, 0.f) + __logf(1.f + __expf(-fabsf(acc)));
        ushort u = f2bf(sp);
        if (j == 0) o.x = u; else if (j == 1) o.y = u;
        else if (j == 2) o.z = u; else o.w = u;
    }
    *(ushort4*)(dt_bf + (size_t)row * 512 + n0) = o;
}

// ---------------- causal conv (width 4) + bias + silu, bf16 in/out ---------
__global__ __launch_bounds__(256) void conv_silu_kernel(
    const ushort* __restrict__ xz, const float* __restrict__ cw,
    const float* __restrict__ cb, ushort* __restrict__ xi)
{
    int idx = blockIdx.x * 256 + threadIdx.x;   // over (BL/8)*128
    int d4 = (idx & 127) * 4;
    int grp = idx >> 7;                          // 0 .. BL/8-1
    int b = grp >> 9;                            // LL/8 = 512 groups per b
    int t0 = (grp & 511) * 8;
    const ushort* base = xz + ((size_t)(b * LL + t0) * 1024) + d4;
    ushort* obase = xi + ((size_t)(b * LL + t0) * 512) + d4;

    float4 w0 = *(const float4*)(cw + (d4 + 0) * 4);
    float4 w1 = *(const float4*)(cw + (d4 + 1) * 4);
    float4 w2 = *(const float4*)(cw + (d4 + 2) * 4);
    float4 w3 = *(const float4*)(cw + (d4 + 3) * 4);
    float b0 = cb[d4 + 0], b1 = cb[d4 + 1], b2 = cb[d4 + 2], b3 = cb[d4 + 3];

    ushort4 z4 = {0, 0, 0, 0};
    ushort4 win0 = (t0 >= 3) ? *(const ushort4*)(base - 3 * 1024) : z4;
    ushort4 win1 = (t0 >= 2) ? *(const ushort4*)(base - 2 * 1024) : z4;
    ushort4 win2 = (t0 >= 1) ? *(const ushort4*)(base - 1 * 1024) : z4;

    #pragma unroll
    for (int k = 0; k < 8; ++k) {
        ushort4 cur = *(const ushort4*)(base + k * 1024);
        float a0 = b0, a1 = b1, a2 = b2, a3 = b3;
        a0 = fmaf(bf2f(win0.x), w0.x, a0); a1 = fmaf(bf2f(win0.y), w1.x, a1);
        a2 = fmaf(bf2f(win0.z), w2.x, a2); a3 = fmaf(bf2f(win0.w), w3.x, a3);
        a0 = fmaf(bf2f(win1.x), w0.y, a0); a1 = fmaf(bf2f(win1.y), w1.y, a1);
        a2 = fmaf(bf2f(win1.z), w2.y, a2); a3 = fmaf(bf2f(win1.w), w3.y, a3);
        a0 = fmaf(bf2f(win2.x), w0.z, a0); a1 = fmaf(bf2f(win2.y), w1.z, a1);
        a2 = fmaf(bf2f(win2.z), w2.z, a2); a3 = fmaf(bf2f(win2.w), w3.z, a3);
        a0 = fmaf(bf2f(cur.x),  w0.w, a0); a1 = fmaf(bf2f(cur.y),  w1.w, a1);
        a2 = fmaf(bf2f(cur.z),  w2.w, a2); a3 = fmaf(bf2f(cur.w),  w3.w, a3);
        ushort4 o;
        o.x = f2bf(a0 / (1.f + __expf(-a0)));
        o.y = f2bf(a1 / (1.f + __expf(-a1)));
        o.z = f2bf(a2 / (1.f + __expf(-a2)));
        o.w = f2bf(a3 / (1.f + __expf(-a3)));
        *(ushort4*)(obase + k * 512) = o;
        win0 = win1; win1 = win2; win2 = cur;
    }
}

// ---------------- chunked selective scan -----------------------------------
__global__ __launch_bounds__(256) void scan_phase1(
    const ushort* __restrict__ xi, const ushort* __restrict__ dtb,
    const float* __restrict__ bc,
    const float* __restrict__ alog,
    float* __restrict__ cS, float* __restrict__ cH)
{
    int d = blockIdx.z * 256 + threadIdx.x;
    int b = blockIdx.y, c = blockIdx.x;
    float Av[16];
    bool fast = true;
    #pragma unroll
    for (int s = 0; s < 16; ++s) {
        Av[s] = -__expf(alog[d * 16 + s]);
        fast = fast && (fabsf(Av[s] + (float)(s + 1)) < 1e-3f * (s + 1));
    }
    float h[16];
    #pragma unroll
    for (int s = 0; s < 16; ++s) h[s] = 0.f;
    float S = 0.f;
    int t0 = c * CLEN;
    if (fast) {
        for (int t = t0; t < t0 + CLEN; ++t) {
            size_t row = (size_t)b * LL + t;
            float dt = bf2f(dtb[row * 512 + d]);
            float x = bf2f(xi[row * 512 + d]);
            float dtx = dt * x;
            S += dt;
            const float* bp = bc + row * 32;
            float e1 = __expf(-dt);
            float e2=e1*e1, e3=e2*e1, e4=e2*e2, e5=e3*e2, e6=e3*e3, e7=e4*e3, e8=e4*e4;
            float e9=e5*e4, e10=e5*e5, e11=e6*e5, e12=e6*e6, e13=e7*e6, e14=e7*e7, e15=e8*e7, e16=e8*e8;
            float pw[16] = {e1,e2,e3,e4,e5,e6,e7,e8,e9,e10,e11,e12,e13,e14,e15,e16};
            #pragma unroll
            for (int s = 0; s < 16; ++s)
                h[s] = fmaf(pw[s], h[s], dtx * bp[s]);
        }
    } else {
        for (int t = t0; t < t0 + CLEN; ++t) {
            size_t row = (size_t)b * LL + t;
            float dt = bf2f(dtb[row * 512 + d]);
            float x = bf2f(xi[row * 512 + d]);
            float dtx = dt * x;
            S += dt;
            const float* bp = bc + row * 32;
            #pragma unroll
            for (int s = 0; s < 16; ++s) {
                float dA = __expf(dt * Av[s]);
                h[s] = fmaf(dA, h[s], dtx * bp[s]);
            }
        }
    }
    cS[((size_t)b * DI + d) * NC + c] = S;
    size_t base = (((size_t)b * DI + d) * NC + c) * 16;
    #pragma unroll
    for (int q = 0; q < 4; ++q)
        *(float4*)(cH + base + q*4) = *(float4*)&h[q*4];
}

// Parallel chunk-prefix: one block per (b,d); 16 threads per s-value,
// each composing 8 chunks; shfl-scan of affine maps F(x)=Ax+H across the
// 16-lane segment (serial chain 128 -> 8+4+8). Decay a = exp(Av[s]*S).
__global__ __launch_bounds__(256) void scan_phase2(
    const float* __restrict__ cS, float* __restrict__ cH,
    const float* __restrict__ alog)
{
    int bd = blockIdx.x;            // b*DI + d
    int d = bd & (DI - 1);
    int tid = threadIdx.x;
    int s = tid >> 4;               // 0..15
    int g = tid & 15;               // chunk group (8 chunks each)
    float Avs = -__expf(alog[d * 16 + s]);
    size_t sbase = (size_t)bd * NC;
    size_t base = (size_t)bd * NC * 16 + s;
    float a8[8], h8[8];
    #pragma unroll
    for (int j = 0; j < 8; ++j) {
        float Sj = cS[sbase + g * 8 + j];
        a8[j] = __expf(Avs * Sj);
        h8[j] = cH[base + (size_t)(g * 8 + j) * 16];
    }
    float A = 1.f, H = 0.f;
    #pragma unroll
    for (int j = 0; j < 8; ++j) {
        H = fmaf(a8[j], H, h8[j]);
        A *= a8[j];
    }
    #pragma unroll
    for (int off = 1; off < 16; off <<= 1) {
        float Ap = __shfl_up(A, off, 16);
        float Hp = __shfl_up(H, off, 16);
        if (g >= off) { H = fmaf(A, Hp, H); A *= Ap; }
    }
    float init = __shfl_up(H, 1, 16);
    if (g == 0) init = 0.f;
    #pragma unroll
    for (int j = 0; j < 8; ++j) {
        size_t o = base + (size_t)(g * 8 + j) * 16;
        cH[o] = init;
        init = fmaf(a8[j], init, h8[j]);
    }
}

__global__ __launch_bounds__(256) void scan_phase3(
    const ushort* __restrict__ xz,   // bf16, ld 1024; res at cols 512..1023
    ushort* __restrict__ xi,
    const ushort* __restrict__ dtb,
    const float* __restrict__ bc,
    const float* __restrict__ alog,
    const float* __restrict__ Dp,
    const float* __restrict__ cH,
    int c0)
{
    int d = blockIdx.z * 256 + threadIdx.x;
    int b = blockIdx.y;
    int c = blockIdx.x + c0;
    float Av[16];
    bool fast = true;
    #pragma unroll
    for (int s = 0; s < 16; ++s) {
        Av[s] = -__expf(alog[d * 16 + s]);
        fast = fast && (fabsf(Av[s] + (float)(s + 1)) < 1e-3f * (s + 1));
    }
    float h[16];
    size_t cbase = (((size_t)b * DI + d) * NC + c) * 16;
    #pragma unroll
    for (int q = 0; q < 4; ++q)
        *(float4*)&h[q*4] = *(const float4*)(cH + cbase + q*4);
    float Dd = Dp[d];
    int t0 = c * CLEN;
    if (fast) {
        for (int t = t0; t < t0 + CLEN; ++t) {
            size_t row = (size_t)b * LL + t;
            float dt = bf2f(dtb[row * 512 + d]);
            float x = bf2f(xi[row * 512 + d]);
            float dtx = dt * x;
            const float* bp = bc + row * 32;
            const float* cp = bc + row * 32 + 16;
            float e1 = __expf(-dt);
            float e2=e1*e1, e3=e2*e1, e4=e2*e2, e5=e3*e2, e6=e3*e3, e7=e4*e3, e8=e4*e4;
            float e9=e5*e4, e10=e5*e5, e11=e6*e5, e12=e6*e6, e13=e7*e6, e14=e7*e7, e15=e8*e7, e16=e8*e8;
            float pw[16] = {e1,e2,e3,e4,e5,e6,e7,e8,e9,e10,e11,e12,e13,e14,e15,e16};
            float y = 0.f;
            #pragma unroll
            for (int s = 0; s < 16; ++s) {
                h[s] = fmaf(pw[s], h[s], dtx * bp[s]);
                y = fmaf(h[s], cp[s], y);
            }
            float res = bf2f(xz[row * 1024 + 512 + d]);
            float g = (y + x * Dd) * (res / (1.f + __expf(-res)));
            xi[row * 512 + d] = f2bf(g);
        }
    } else {
        for (int t = t0; t < t0 + CLEN; ++t) {
            size_t row = (size_t)b * LL + t;
            float dt = bf2f(dtb[row * 512 + d]);
            float x = bf2f(xi[row * 512 + d]);
            float dtx = dt * x;
            const float* bp = bc + row * 32;
            const float* cp = bc + row * 32 + 16;
            float y = 0.f;
            #pragma unroll
            for (int s = 0; s < 16; ++s) {
                float dA = __expf(dt * Av[s]);
                h[s] = fmaf(dA, h[s], dtx * bp[s]);
                y = fmaf(h[s], cp[s], y);
            }
            float res = bf2f(xz[row * 1024 + 512 + d]);
            float g = (y + x * Dd) * (res / (1.f + __expf(-res)));
            xi[row * 512 + d] = f2bf(g);
        }
    }
}

// ---------------- last-row out_proj (layer 2) ------------------------------
// hlast[b][n] = bf16_resid(h_bf last row) + out_proj(y last row)
__global__ __launch_bounds__(256) void out_proj_last_kernel(
    const ushort* __restrict__ xi, const float* __restrict__ W,
    const ushort* __restrict__ hbf, float* __restrict__ hlast)
{
    int b = blockIdx.x, n = threadIdx.x;
    __shared__ float sy[DI];
    const ushort* yrow = xi + ((size_t)b * LL + (LL - 1)) * DI;
    for (int k = threadIdx.x; k < DI; k += 256) sy[k] = bf2f(yrow[k]);
    __syncthreads();
    const float* wr = W + (size_t)n * DI;
    float acc = 0.f;
    for (int k = 0; k < DI; k += 4) {
        float4 wv = *(const float4*)(wr + k);
        acc = fmaf(sy[k+0], wv.x, acc);
        acc = fmaf(sy[k+1], wv.y, acc);
        acc = fmaf(sy[k+2], wv.z, acc);
        acc = fmaf(sy[k+3], wv.w, acc);
    }
    hlast[b * DM + n] = acc + bf2f(hbf[((size_t)b * LL + (LL - 1)) * DM + n]);
}

// ---------------- final LN (last row only) + head --------------------------
__global__ __launch_bounds__(256) void ln_head_kernel(
    const float* __restrict__ hlast, const float* __restrict__ lng,
    const float* __restrict__ lnb, const float* __restrict__ hw,
    const float* __restrict__ hb, float* __restrict__ out)
{
    int b = blockIdx.x, tid = threadIdx.x;
    __shared__ float sh[DM];
    __shared__ float r1[4], r2[4];
    float v = hlast[b * DM + tid];
    float s = v;
    #pragma unroll
    for (int o = 32; o >= 1; o >>= 1) s += __shfl_down(s, o);
    if ((tid & 63) == 0) r1[tid >> 6] = s;
    __syncthreads();
    float mu = (r1[0] + r1[1] + r1[2] + r1[3]) * (1.f / 256.f);
    float dv = v - mu;
    float q = dv * dv;
    #pragma unroll
    for (int o = 32; o >= 1; o >>= 1) q += __shfl_down(q, o);
    if ((tid & 63) == 0) r2[tid >> 6] = q;
    __syncthreads();
    float var = (r2[0] + r2[1] + r2[2] + r2[3]) * (1.f / 256.f);
    sh[tid] = dv * rsqrtf(var + LN_EPS) * lng[tid] + lnb[tid];
    __syncthreads();
    if (tid < NOUTK) {
        const float* wr = hw + (size_t)tid * DM;
        float acc = hb[tid];
        for (int d2 = 0; d2 < DM; d2 += 4) {
            float4 wv = *(const float4*)(wr + d2);
            acc = fmaf(sh[d2+0], wv.x, acc);
            acc = fmaf(sh[d2+1], wv.y, acc);
            acc = fmaf(sh[d2+2], wv.z, acc);
            acc = fmaf(sh[d2+3], wv.w, acc);
        }
        out[b * NOUTK + tid] = acc;
    }
}

extern "C" void kernel_launch(void* const* d_in, const int* in_sizes, int n_in,
                              void* d_out, int out_size, void* d_ws, size_t ws_size,
                              hipStream_t stream)
{
    const float* x    = (const float*)d_in[0];
    const float* encw = (const float*)d_in[1];
    const float* encb = (const float*)d_in[2];
    const float* inw  = (const float*)d_in[3];
    const float* cw   = (const float*)d_in[4];
    const float* cb   = (const float*)d_in[5];
    const float* xpw  = (const float*)d_in[6];
    const float* dtw  = (const float*)d_in[7];
    const float* dtb  = (const float*)d_in[8];
    const float* alog = (const float*)d_in[9];
    const float* Dp   = (const float*)d_in[10];
    const float* opw  = (const float*)d_in[11];
    const float* lng  = (const float*)d_in[12];
    const float* lnb  = (const float*)d_in[13];
    const float* hw   = (const float*)d_in[14];
    const float* hb   = (const float*)d_in[15];
    float* out = (float*)d_out;

    float* ws   = (float*)d_ws;
    float* bc   = ws;                               // BL*32 f32 (B|C)
    float* cS   = bc  + (size_t)BL * 32;            // B*DI*NC f32 (sum dt)
    float* cH   = cS  + (size_t)BB * DI * NC;       // B*DI*NC*16 f32
    float* r16  = cH  + (size_t)BB * DI * NC * DS;  // BL*16 f32
    float* hlast = r16 + (size_t)BL * 16;           // BB*DM f32
    ushort* h_bf    = (ushort*)(hlast + BB * DM);   // BL*256 (residual stream)
    ushort* xz_bf   = h_bf  + (size_t)BL * DM;      // BL*1024
    ushort* xi_bf   = xz_bf + (size_t)BL * 1024;    // BL*512
    ushort* dt_bf   = xi_bf + (size_t)BL * DI;      // BL*512 (softplus'd dt)
    ushort* inw_bf  = dt_bf + (size_t)BL * DI;      // 2*1024*256
    ushort* opw_bf  = inw_bf + 2 * 1024 * DM;       // 2*256*512
    ushort* xpw48_bf = opw_bf + 2 * DM * DI;        // 2*64*512 (rows 48-63 = 0)

    dim3 blk(256, 1, 1);

    prep_enc_kernel<<<dim3(PREP_BLOCKS + ENC_BLOCKS), blk, 0, stream>>>(
        inw, opw, xpw, inw_bf, opw_bf, xpw48_bf,
        x, encw, encb, h_bf);

    for (int l = 0; l < 2; ++l) {
        // in_proj -> xz_bf (bf16 only)
        mfma_gemm<0><<<dim3(1024/128, BL/64), blk, 0, stream>>>(
            h_bf, DM, inw_bf + (size_t)l * 1024 * DM,
            xz_bf, 1024, DM);
        // conv + silu -> xi_bf
        conv_silu_kernel<<<dim3(BL * 128 / 8 / 256), blk, 0, stream>>>(
            xz_bf, cw + l * DI * 4, cb + l * DI, xi_bf);
        // skinny xproj: [r16 | B | C] = xi @ xpw48^T
        mfma_gemm48<<<dim3(1, BL/64), blk, 0, stream>>>(
            xi_bf, xpw48_bf + (size_t)l * 64 * DI, r16, bc);
        // dt = softplus(r16 @ dtw^T + dtb) -> bf16
        dt_combine_kernel<<<dim3(BL * 128 / 256), blk, 0, stream>>>(
            r16, dtw + (size_t)l * DI * 16, dtb + (size_t)l * DI, dt_bf);
        // scan
        scan_phase1<<<dim3(NC, BB, 2), blk, 0, stream>>>(
            xi_bf, dt_bf, bc, alog + (size_t)l * DI * 16, cS, cH);
        scan_phase2<<<dim3(BB * DI), blk, 0, stream>>>(
            cS, cH, alog + (size_t)l * DI * 16);
        if (l == 0) {
            scan_phase3<<<dim3(NC, BB, 2), blk, 0, stream>>>(
                xz_bf, xi_bf, dt_bf, bc, alog + (size_t)l * DI * 16,
                Dp + l * DI, cH, 0);
            // out_proj with bf16 residual read-modify-write on h_bf
            mfma_gemm<2><<<dim3(DM/128, BL/64), blk, 0, stream>>>(
                xi_bf, DI, opw_bf + (size_t)l * DM * DI,
                h_bf, DM, DI);
        } else {
            scan_phase3<<<dim3(1, BB, 2), blk, 0, stream>>>(
                xz_bf, xi_bf, dt_bf, bc, alog + (size_t)l * DI * 16,
                Dp + l * DI, cH, NC - 1);
            out_proj_last_kernel<<<dim3(BB), blk, 0, stream>>>(
                xi_bf, opw + (size_t)l * DM * DI, h_bf, hlast);
        }
    }

    ln_head_kernel<<<dim3(BB), blk, 0, stream>>>(hlast, lng, lnb, hw, hb, out);
}

// Round 10
// 318.619 us; speedup vs baseline: 1.2563x; 1.2563x over previous
//
#include <hip/hip_runtime.h>
#include <hip/hip_bf16.h>
#include <math.h>

#define BB 4
#define LL 4096
#define DM 256
#define DI 512
#define DS 16
#define NOUTK 128
#define LN_EPS 1e-5f
#define NC 128
#define CLEN (LL/NC)
#define BL (BB*LL)

typedef __attribute__((ext_vector_type(8))) short short8;
typedef __attribute__((ext_vector_type(4))) float f32x4;

__device__ __forceinline__ ushort f2bf(float f) {
    union { float f; unsigned u; } v; v.f = f;
    unsigned r = (v.u + 0x7FFF + ((v.u >> 16) & 1)) >> 16;
    return (ushort)r;
}
__device__ __forceinline__ float bf2f(ushort u) {
    union { unsigned u; float f; } v; v.u = ((unsigned)u) << 16;
    return v.f;
}

// ---------------- fused weight prep + encoder ------------------------------
// Blocks [0, PREP_BLOCKS): weight prep (inw/opw cast, xpw48 cast, dtwT).
// Blocks [PREP_BLOCKS, ...): encoder rows.
#define PREP_N1 (2*1024*256)
#define PREP_N2 (2*256*512)
#define PREP_N3 (2*64*512)     /* xpw rows 0..47 cast to bf16, padded to 64 */
#define PREP_N4 (2*16*512)     /* dtw transposed to [k][n], f32 */
#define PREP_BLOCKS ((PREP_N1 + PREP_N2 + PREP_N3 + PREP_N4) / 256)
#define ENC_BLOCKS (BL / 4)
__global__ __launch_bounds__(256) void prep_enc_kernel(
    const float* __restrict__ inw, const float* __restrict__ opw,
    const float* __restrict__ xpw, const float* __restrict__ dtw,
    ushort* __restrict__ inw_bf, ushort* __restrict__ opw_bf,
    ushort* __restrict__ xpw48_bf, float* __restrict__ dtwT,
    const float* __restrict__ x, const float* __restrict__ encw,
    const float* __restrict__ encb, ushort* __restrict__ hbf)
{
    int tid = threadIdx.x;
    if (blockIdx.x < PREP_BLOCKS) {
        int i = blockIdx.x * 256 + tid;
        if (i < PREP_N1) {
            inw_bf[i] = f2bf(inw[i]);
            return;
        }
        int j = i - PREP_N1;
        if (j < PREP_N2) {
            opw_bf[j] = f2bf(opw[j]);
            return;
        }
        int m = j - PREP_N2;
        if (m < PREP_N3) {
            int l = m / (64 * 512);
            int rem = m - l * 64 * 512;
            int row = rem >> 9, k = rem & 511;
            float v = (row < 48) ? xpw[(size_t)l * 48 * 512 + row * 512 + k] : 0.f;
            xpw48_bf[m] = f2bf(v);
            return;
        }
        int m2 = m - PREP_N3;
        if (m2 >= PREP_N4) return;
        int l = m2 / (16 * 512);
        int rem = m2 - l * 16 * 512;
        int k = rem >> 9, n = rem & 511;
        dtwT[m2] = dtw[(size_t)l * 512 * 16 + n * 16 + k];
        return;
    }
    // ---- encoder branch ----
    __shared__ float sw[256 * 33];
    __shared__ float sx[4][32];
    for (int i = tid; i < 256 * 8; i += 256) {
        float4 v = ((const float4*)encw)[i];
        int r = i >> 3, c = (i & 7) * 4;
        sw[r * 33 + c + 0] = v.x; sw[r * 33 + c + 1] = v.y;
        sw[r * 33 + c + 2] = v.z; sw[r * 33 + c + 3] = v.w;
    }
    int row0 = (blockIdx.x - PREP_BLOCKS) * 4;
    if (tid < 32) {
        for (int rr = 0; rr < 4; ++rr)
            sx[rr][tid] = x[(size_t)(row0 + rr) * 32 + tid];
    }
    __syncthreads();
    float bb = encb[tid];
    #pragma unroll
    for (int rr = 0; rr < 4; ++rr) {
        float acc = bb;
        #pragma unroll
        for (int k = 0; k < 32; ++k)
            acc = fmaf(sx[rr][k], sw[tid * 33 + k], acc);
        hbf[(size_t)(row0 + rr) * DM + tid] = f2bf(acc);
    }
}

// ---------------- bf16 MFMA GEMM: C = epi(A @ W^T) -------------------------
// Tile 64(M) x 128(N), 4 waves of 32x64, single-buffered 24 KB LDS
// (m97-style 2-barrier k-loop; latency hidden by co-resident blocks).
// FROZEN CONFIG. Post-mortems:
//  R3: explicit LDS double-buffer (48 KB) -> -31 us (residency 6->3).
//  R5: forced launch_bounds(256,6) -> spill, flat despite traffic cuts.
//  R7: LDS-free direct fragment loads -> 2x SLOWER (each wave load touches
//      16 cache lines; LDS staging IS the coalescing transform here).
// EPI: 0 plain bf16 out; 2 residual bf16 read-modify-write on Cbf.
template<int EPI>
__global__ __launch_bounds__(256, 4) void mfma_gemm(
    const ushort* __restrict__ A, int lda,
    const ushort* __restrict__ W,
    ushort* Cbf, int ldcbf,
    int K)
{
    __shared__ ushort As[64 * 64];
    __shared__ ushort Ws[128 * 64];
    const int tid = threadIdx.x;

    // XCD-aware bijective swizzle (nwg % 8 == 0 for all our launches)
    int nwg = gridDim.x * gridDim.y;
    int wlin = blockIdx.y * gridDim.x + blockIdx.x;
    int gx = blockIdx.x, gy = blockIdx.y;
    if ((nwg & 7) == 0) {
        int q = nwg >> 3;
        int s = (wlin & 7) * q + (wlin >> 3);
        gx = s % gridDim.x;
        gy = s / gridDim.x;
    }
    const int bm = gy * 64;
    const int bn = gx * 128;
    const int wid = tid >> 6, lane = tid & 63;
    const int wrow = (wid >> 1) * 32, wcol = (wid & 1) * 64;
    const int sr = tid >> 3;
    const int sc = tid & 7;

    f32x4 acc[2][4];
    #pragma unroll
    for (int mi = 0; mi < 2; ++mi)
        #pragma unroll
        for (int ni = 0; ni < 4; ++ni)
            acc[mi][ni] = (f32x4){0.f, 0.f, 0.f, 0.f};

    const int nk = K >> 6;          // 4 (K=256) or 8 (K=512)
    for (int t = 0; t < nk; ++t) {
        const int k0 = t << 6;
        #pragma unroll
        for (int it = 0; it < 2; ++it) {
            int r = it * 32 + sr;
            int csrc = sc ^ (r & 7);
            __builtin_amdgcn_global_load_lds(
                (const __attribute__((address_space(1))) unsigned int*)
                    (A + (size_t)(bm + r) * lda + k0 + csrc * 8),
                (__attribute__((address_space(3))) unsigned int*)
                    (As + r * 64 + sc * 8), 16, 0, 0);
        }
        #pragma unroll
        for (int it = 0; it < 4; ++it) {
            int r = it * 32 + sr;
            int csrc = sc ^ (r & 7);
            __builtin_amdgcn_global_load_lds(
                (const __attribute__((address_space(1))) unsigned int*)
                    (W + (size_t)(bn + r) * K + k0 + csrc * 8),
                (__attribute__((address_space(3))) unsigned int*)
                    (Ws + r * 64 + sc * 8), 16, 0, 0);
        }
        __syncthreads();
        #pragma unroll
        for (int kk = 0; kk < 2; ++kk) {
            short8 af[2], bfr[4];
            #pragma unroll
            for (int mi = 0; mi < 2; ++mi) {
                int r = wrow + mi * 16 + (lane & 15);
                int c = (lane >> 4) + kk * 4;
                af[mi] = *(const short8*)(As + r * 64 + ((c ^ (r & 7)) << 3));
            }
            #pragma unroll
            for (int ni = 0; ni < 4; ++ni) {
                int r = wcol + ni * 16 + (lane & 15);
                int c = (lane >> 4) + kk * 4;
                bfr[ni] = *(const short8*)(Ws + r * 64 + ((c ^ (r & 7)) << 3));
            }
            #pragma unroll
            for (int mi = 0; mi < 2; ++mi)
                #pragma unroll
                for (int ni = 0; ni < 4; ++ni)
                    acc[mi][ni] = __builtin_amdgcn_mfma_f32_16x16x32_bf16(
                        af[mi], bfr[ni], acc[mi][ni], 0, 0, 0);
        }
        __syncthreads();
    }

    #pragma unroll
    for (int mi = 0; mi < 2; ++mi)
        #pragma unroll
        for (int ni = 0; ni < 4; ++ni) {
            int col = bn + wcol + ni * 16 + (lane & 15);
            #pragma unroll
            for (int r = 0; r < 4; ++r) {
                int row = bm + wrow + mi * 16 + (lane >> 4) * 4 + r;
                float v = acc[mi][ni][r];
                if (EPI == 2) {
                    size_t o = (size_t)row * ldcbf + col;
                    float vv = v + bf2f(Cbf[o]);
                    Cbf[o] = f2bf(vv);
                } else {
                    Cbf[(size_t)row * ldcbf + col] = f2bf(v);
                }
            }
        }
}

// ---------------- skinny xproj GEMM: [r16 | B | C] = xi @ xpw48^T ----------
// M=64 x N=64 tile (N=48 useful), 4 waves of 16x64, 16 KB LDS, same
// verified k-loop/fragment pattern as mfma_gemm. Grid (1, BL/64) = 256
// blocks = 1/CU; single round -> per-block latency paid once.
// Rank-16 factorization: dt is finished by dt_combine (K=16, f32).
__global__ __launch_bounds__(256, 4) void mfma_gemm48(
    const ushort* __restrict__ A,      // xi_bf, lda = 512
    const ushort* __restrict__ W,      // xpw48_bf layer base: 64 x 512
    float* __restrict__ r16,           // BL x 16 f32
    float* __restrict__ bc)            // BL x 32 f32
{
    __shared__ ushort As[64 * 64];
    __shared__ ushort Ws[64 * 64];
    const int tid = threadIdx.x;

    int nwg = gridDim.y;               // 256
    int wlin = blockIdx.y;
    int gy = wlin;
    if ((nwg & 7) == 0) {
        int q = nwg >> 3;
        gy = (wlin & 7) * q + (wlin >> 3);
    }
    const int bm = gy * 64;
    const int wid = tid >> 6, lane = tid & 63;
    const int wrow = wid * 16;
    const int sr = tid >> 3;
    const int sc = tid & 7;

    f32x4 acc[4];
    #pragma unroll
    for (int ni = 0; ni < 4; ++ni)
        acc[ni] = (f32x4){0.f, 0.f, 0.f, 0.f};

    for (int t = 0; t < 8; ++t) {      // K = 512
        const int k0 = t << 6;
        #pragma unroll
        for (int it = 0; it < 2; ++it) {
            int r = it * 32 + sr;
            int csrc = sc ^ (r & 7);
            __builtin_amdgcn_global_load_lds(
                (const __attribute__((address_space(1))) unsigned int*)
                    (A + (size_t)(bm + r) * DI + k0 + csrc * 8),
                (__attribute__((address_space(3))) unsigned int*)
                    (As + r * 64 + sc * 8), 16, 0, 0);
        }
        #pragma unroll
        for (int it = 0; it < 2; ++it) {
            int r = it * 32 + sr;
            int csrc = sc ^ (r & 7);
            __builtin_amdgcn_global_load_lds(
                (const __attribute__((address_space(1))) unsigned int*)
                    (W + (size_t)r * DI + k0 + csrc * 8),
                (__attribute__((address_space(3))) unsigned int*)
                    (Ws + r * 64 + sc * 8), 16, 0, 0);
        }
        __syncthreads();
        #pragma unroll
        for (int kk = 0; kk < 2; ++kk) {
            int c = (lane >> 4) + kk * 4;
            int ra = wrow + (lane & 15);
            short8 af = *(const short8*)(As + ra * 64 + ((c ^ (ra & 7)) << 3));
            #pragma unroll
            for (int ni = 0; ni < 4; ++ni) {
                int rb = ni * 16 + (lane & 15);
                short8 bfr = *(const short8*)(Ws + rb * 64 + ((c ^ (rb & 7)) << 3));
                acc[ni] = __builtin_amdgcn_mfma_f32_16x16x32_bf16(
                    af, bfr, acc[ni], 0, 0, 0);
            }
        }
        __syncthreads();
    }

    #pragma unroll
    for (int ni = 0; ni < 3; ++ni) {   // cols 48-63 are zero-pad, skip ni=3
        int col = ni * 16 + (lane & 15);
        #pragma unroll
        for (int r = 0; r < 4; ++r) {
            int row = bm + wrow + (lane >> 4) * 4 + r;
            float v = acc[ni][r];
            if (col < 16) r16[(size_t)row * 16 + col] = v;
            else          bc[(size_t)row * 32 + (col - 16)] = v;
        }
    }
}

// ---------------- dt finish: dt = softplus(r16 @ dtw^T + dtb), bf16 --------
// Uses TRANSPOSED dtwT[k][n]: lane i reads dtwT[k][n0..n0+3] -> 64 lanes x
// 16 B = one contiguous 1 KB segment per load (L1-resident). R9's version
// read dtw row-major: 64 distinct cache lines per load -> 69 us stall.
// r16 row is wave-uniform (row = idx>>7, const across 64 lanes) -> s_load.
__global__ __launch_bounds__(256) void dt_combine_kernel(
    const float* __restrict__ r16, const float* __restrict__ dtwT,
    const float* __restrict__ dtb, ushort* __restrict__ dt_bf)
{
    int idx = blockIdx.x * 256 + threadIdx.x;   // over BL*128
    int n0 = (idx & 127) * 4;
    int row = idx >> 7;
    const float* rp = r16 + (size_t)row * 16;
    float4 acc = *(const float4*)(dtb + n0);
    #pragma unroll
    for (int k = 0; k < 16; ++k) {
        float rk = rp[k];
        float4 wv = *(const float4*)(dtwT + k * 512 + n0);
        acc.x = fmaf(rk, wv.x, acc.x);
        acc.y = fmaf(rk, wv.y, acc.y);
        acc.z = fmaf(rk, wv.z, acc.z);
        acc.w = fmaf(rk, wv.w, acc.w);
    }
    ushort4 o;
    o.x = f2bf(fmaxf(acc.x, 0.f) + __logf(1.f + __expf(-fabsf(acc.x))));
    o.y = f2bf(fmaxf(acc.y, 0.f) + __logf(1.f + __expf(-fabsf(acc.y))));
    o.z = f2bf(fmaxf(acc.z, 0.f) + __logf(1.f + __expf(-fabsf(acc.z))));
    o.w = f2bf(fmaxf(acc.w, 0.f) + __logf(1.f + __expf(-fabsf(acc.w))));
    *(ushort4*)(dt_bf + (size_t)row * 512 + n0) = o;
}

// ---------------- causal conv (width 4) + bias + silu, bf16 in/out ---------
__global__ __launch_bounds__(256) void conv_silu_kernel(
    const ushort* __restrict__ xz, const float* __restrict__ cw,
    const float* __restrict__ cb, ushort* __restrict__ xi)
{
    int idx = blockIdx.x * 256 + threadIdx.x;   // over (BL/8)*128
    int d4 = (idx & 127) * 4;
    int grp = idx >> 7;                          // 0 .. BL/8-1
    int b = grp >> 9;                            // LL/8 = 512 groups per b
    int t0 = (grp & 511) * 8;
    const ushort* base = xz + ((size_t)(b * LL + t0) * 1024) + d4;
    ushort* obase = xi + ((size_t)(b * LL + t0) * 512) + d4;

    float4 w0 = *(const float4*)(cw + (d4 + 0) * 4);
    float4 w1 = *(const float4*)(cw + (d4 + 1) * 4);
    float4 w2 = *(const float4*)(cw + (d4 + 2) * 4);
    float4 w3 = *(const float4*)(cw + (d4 + 3) * 4);
    float b0 = cb[d4 + 0], b1 = cb[d4 + 1], b2 = cb[d4 + 2], b3 = cb[d4 + 3];

    ushort4 z4 = {0, 0, 0, 0};
    ushort4 win0 = (t0 >= 3) ? *(const ushort4*)(base - 3 * 1024) : z4;
    ushort4 win1 = (t0 >= 2) ? *(const ushort4*)(base - 2 * 1024) : z4;
    ushort4 win2 = (t0 >= 1) ? *(const ushort4*)(base - 1 * 1024) : z4;

    #pragma unroll
    for (int k = 0; k < 8; ++k) {
        ushort4 cur = *(const ushort4*)(base + k * 1024);
        float a0 = b0, a1 = b1, a2 = b2, a3 = b3;
        a0 = fmaf(bf2f(win0.x), w0.x, a0); a1 = fmaf(bf2f(win0.y), w1.x, a1);
        a2 = fmaf(bf2f(win0.z), w2.x, a2); a3 = fmaf(bf2f(win0.w), w3.x, a3);
        a0 = fmaf(bf2f(win1.x), w0.y, a0); a1 = fmaf(bf2f(win1.y), w1.y, a1);
        a2 = fmaf(bf2f(win1.z), w2.y, a2); a3 = fmaf(bf2f(win1.w), w3.y, a3);
        a0 = fmaf(bf2f(win2.x), w0.z, a0); a1 = fmaf(bf2f(win2.y), w1.z, a1);
        a2 = fmaf(bf2f(win2.z), w2.z, a2); a3 = fmaf(bf2f(win2.w), w3.z, a3);
        a0 = fmaf(bf2f(cur.x),  w0.w, a0); a1 = fmaf(bf2f(cur.y),  w1.w, a1);
        a2 = fmaf(bf2f(cur.z),  w2.w, a2); a3 = fmaf(bf2f(cur.w),  w3.w, a3);
        ushort4 o;
        o.x = f2bf(a0 / (1.f + __expf(-a0)));
        o.y = f2bf(a1 / (1.f + __expf(-a1)));
        o.z = f2bf(a2 / (1.f + __expf(-a2)));
        o.w = f2bf(a3 / (1.f + __expf(-a3)));
        *(ushort4*)(obase + k * 512) = o;
        win0 = win1; win1 = win2; win2 = cur;
    }
}

// ---------------- chunked selective scan -----------------------------------
__global__ __launch_bounds__(256) void scan_phase1(
    const ushort* __restrict__ xi, const ushort* __restrict__ dtb,
    const float* __restrict__ bc,
    const float* __restrict__ alog,
    float* __restrict__ cS, float* __restrict__ cH)
{
    int d = blockIdx.z * 256 + threadIdx.x;
    int b = blockIdx.y, c = blockIdx.x;
    float Av[16];
    bool fast = true;
    #pragma unroll
    for (int s = 0; s < 16; ++s) {
        Av[s] = -__expf(alog[d * 16 + s]);
        fast = fast && (fabsf(Av[s] + (float)(s + 1)) < 1e-3f * (s + 1));
    }
    float h[16];
    #pragma unroll
    for (int s = 0; s < 16; ++s) h[s] = 0.f;
    float S = 0.f;
    int t0 = c * CLEN;
    if (fast) {
        for (int t = t0; t < t0 + CLEN; ++t) {
            size_t row = (size_t)b * LL + t;
            float dt = bf2f(dtb[row * 512 + d]);
            float x = bf2f(xi[row * 512 + d]);
            float dtx = dt * x;
            S += dt;
            const float* bp = bc + row * 32;
            float e1 = __expf(-dt);
            float e2=e1*e1, e3=e2*e1, e4=e2*e2, e5=e3*e2, e6=e3*e3, e7=e4*e3, e8=e4*e4;
            float e9=e5*e4, e10=e5*e5, e11=e6*e5, e12=e6*e6, e13=e7*e6, e14=e7*e7, e15=e8*e7, e16=e8*e8;
            float pw[16] = {e1,e2,e3,e4,e5,e6,e7,e8,e9,e10,e11,e12,e13,e14,e15,e16};
            #pragma unroll
            for (int s = 0; s < 16; ++s)
                h[s] = fmaf(pw[s], h[s], dtx * bp[s]);
        }
    } else {
        for (int t = t0; t < t0 + CLEN; ++t) {
            size_t row = (size_t)b * LL + t;
            float dt = bf2f(dtb[row * 512 + d]);
            float x = bf2f(xi[row * 512 + d]);
            float dtx = dt * x;
            S += dt;
            const float* bp = bc + row * 32;
            #pragma unroll
            for (int s = 0; s < 16; ++s) {
                float dA = __expf(dt * Av[s]);
                h[s] = fmaf(dA, h[s], dtx * bp[s]);
            }
        }
    }
    cS[((size_t)b * DI + d) * NC + c] = S;
    size_t base = (((size_t)b * DI + d) * NC + c) * 16;
    #pragma unroll
    for (int q = 0; q < 4; ++q)
        *(float4*)(cH + base + q*4) = *(float4*)&h[q*4];
}

// Parallel chunk-prefix: one block per (b,d); 16 threads per s-value,
// each composing 8 chunks; shfl-scan of affine maps F(x)=Ax+H across the
// 16-lane segment (serial chain 128 -> 8+4+8). Decay a = exp(Av[s]*S).
__global__ __launch_bounds__(256) void scan_phase2(
    const float* __restrict__ cS, float* __restrict__ cH,
    const float* __restrict__ alog)
{
    int bd = blockIdx.x;            // b*DI + d
    int d = bd & (DI - 1);
    int tid = threadIdx.x;
    int s = tid >> 4;               // 0..15
    int g = tid & 15;               // chunk group (8 chunks each)
    float Avs = -__expf(alog[d * 16 + s]);
    size_t sbase = (size_t)bd * NC;
    size_t base = (size_t)bd * NC * 16 + s;
    float a8[8], h8[8];
    #pragma unroll
    for (int j = 0; j < 8; ++j) {
        float Sj = cS[sbase + g * 8 + j];
        a8[j] = __expf(Avs * Sj);
        h8[j] = cH[base + (size_t)(g * 8 + j) * 16];
    }
    float A = 1.f, H = 0.f;
    #pragma unroll
    for (int j = 0; j < 8; ++j) {
        H = fmaf(a8[j], H, h8[j]);
        A *= a8[j];
    }
    #pragma unroll
    for (int off = 1; off < 16; off <<= 1) {
        float Ap = __shfl_up(A, off, 16);
        float Hp = __shfl_up(H, off, 16);
        if (g >= off) { H = fmaf(A, Hp, H); A *= Ap; }
    }
    float init = __shfl_up(H, 1, 16);
    if (g == 0) init = 0.f;
    #pragma unroll
    for (int j = 0; j < 8; ++j) {
        size_t o = base + (size_t)(g * 8 + j) * 16;
        cH[o] = init;
        init = fmaf(a8[j], init, h8[j]);
    }
}

__global__ __launch_bounds__(256) void scan_phase3(
    const ushort* __restrict__ xz,   // bf16, ld 1024; res at cols 512..1023
    ushort* __restrict__ xi,
    const ushort* __restrict__ dtb,
    const float* __restrict__ bc,
    const float* __restrict__ alog,
    const float* __restrict__ Dp,
    const float* __restrict__ cH,
    int c0)
{
    int d = blockIdx.z * 256 + threadIdx.x;
    int b = blockIdx.y;
    int c = blockIdx.x + c0;
    float Av[16];
    bool fast = true;
    #pragma unroll
    for (int s = 0; s < 16; ++s) {
        Av[s] = -__expf(alog[d * 16 + s]);
        fast = fast && (fabsf(Av[s] + (float)(s + 1)) < 1e-3f * (s + 1));
    }
    float h[16];
    size_t cbase = (((size_t)b * DI + d) * NC + c) * 16;
    #pragma unroll
    for (int q = 0; q < 4; ++q)
        *(float4*)&h[q*4] = *(const float4*)(cH + cbase + q*4);
    float Dd = Dp[d];
    int t0 = c * CLEN;
    if (fast) {
        for (int t = t0; t < t0 + CLEN; ++t) {
            size_t row = (size_t)b * LL + t;
            float dt = bf2f(dtb[row * 512 + d]);
            float x = bf2f(xi[row * 512 + d]);
            float dtx = dt * x;
            const float* bp = bc + row * 32;
            const float* cp = bc + row * 32 + 16;
            float e1 = __expf(-dt);
            float e2=e1*e1, e3=e2*e1, e4=e2*e2, e5=e3*e2, e6=e3*e3, e7=e4*e3, e8=e4*e4;
            float e9=e5*e4, e10=e5*e5, e11=e6*e5, e12=e6*e6, e13=e7*e6, e14=e7*e7, e15=e8*e7, e16=e8*e8;
            float pw[16] = {e1,e2,e3,e4,e5,e6,e7,e8,e9,e10,e11,e12,e13,e14,e15,e16};
            float y = 0.f;
            #pragma unroll
            for (int s = 0; s < 16; ++s) {
                h[s] = fmaf(pw[s], h[s], dtx * bp[s]);
                y = fmaf(h[s], cp[s], y);
            }
            float res = bf2f(xz[row * 1024 + 512 + d]);
            float g = (y + x * Dd) * (res / (1.f + __expf(-res)));
            xi[row * 512 + d] = f2bf(g);
        }
    } else {
        for (int t = t0; t < t0 + CLEN; ++t) {
            size_t row = (size_t)b * LL + t;
            float dt = bf2f(dtb[row * 512 + d]);
            float x = bf2f(xi[row * 512 + d]);
            float dtx = dt * x;
            const float* bp = bc + row * 32;
            const float* cp = bc + row * 32 + 16;
            float y = 0.f;
            #pragma unroll
            for (int s = 0; s < 16; ++s) {
                float dA = __expf(dt * Av[s]);
                h[s] = fmaf(dA, h[s], dtx * bp[s]);
                y = fmaf(h[s], cp[s], y);
            }
            float res = bf2f(xz[row * 1024 + 512 + d]);
            float g = (y + x * Dd) * (res / (1.f + __expf(-res)));
            xi[row * 512 + d] = f2bf(g);
        }
    }
}

// ---------------- last-row out_proj (layer 2) ------------------------------
// hlast[b][n] = bf16_resid(h_bf last row) + out_proj(y last row)
__global__ __launch_bounds__(256) void out_proj_last_kernel(
    const ushort* __restrict__ xi, const float* __restrict__ W,
    const ushort* __restrict__ hbf, float* __restrict__ hlast)
{
    int b = blockIdx.x, n = threadIdx.x;
    __shared__ float sy[DI];
    const ushort* yrow = xi + ((size_t)b * LL + (LL - 1)) * DI;
    for (int k = threadIdx.x; k < DI; k += 256) sy[k] = bf2f(yrow[k]);
    __syncthreads();
    const float* wr = W + (size_t)n * DI;
    float acc = 0.f;
    for (int k = 0; k < DI; k += 4) {
        float4 wv = *(const float4*)(wr + k);
        acc = fmaf(sy[k+0], wv.x, acc);
        acc = fmaf(sy[k+1], wv.y, acc);
        acc = fmaf(sy[k+2], wv.z, acc);
        acc = fmaf(sy[k+3], wv.w, acc);
    }
    hlast[b * DM + n] = acc + bf2f(hbf[((size_t)b * LL + (LL - 1)) * DM + n]);
}

// ---------------- final LN (last row only) + head --------------------------
__global__ __launch_bounds__(256) void ln_head_kernel(
    const float* __restrict__ hlast, const float* __restrict__ lng,
    const float* __restrict__ lnb, const float* __restrict__ hw,
    const float* __restrict__ hb, float* __restrict__ out)
{
    int b = blockIdx.x, tid = threadIdx.x;
    __shared__ float sh[DM];
    __shared__ float r1[4], r2[4];
    float v = hlast[b * DM + tid];
    float s = v;
    #pragma unroll
    for (int o = 32; o >= 1; o >>= 1) s += __shfl_down(s, o);
    if ((tid & 63) == 0) r1[tid >> 6] = s;
    __syncthreads();
    float mu = (r1[0] + r1[1] + r1[2] + r1[3]) * (1.f / 256.f);
    float dv = v - mu;
    float q = dv * dv;
    #pragma unroll
    for (int o = 32; o >= 1; o >>= 1) q += __shfl_down(q, o);
    if ((tid & 63) == 0) r2[tid >> 6] = q;
    __syncthreads();
    float var = (r2[0] + r2[1] + r2[2] + r2[3]) * (1.f / 256.f);
    sh[tid] = dv * rsqrtf(var + LN_EPS) * lng[tid] + lnb[tid];
    __syncthreads();
    if (tid < NOUTK) {
        const float* wr = hw + (size_t)tid * DM;
        float acc = hb[tid];
        for (int d2 = 0; d2 < DM; d2 += 4) {
            float4 wv = *(const float4*)(wr + d2);
            acc = fmaf(sh[d2+0], wv.x, acc);
            acc = fmaf(sh[d2+1], wv.y, acc);
            acc = fmaf(sh[d2+2], wv.z, acc);
            acc = fmaf(sh[d2+3], wv.w, acc);
        }
        out[b * NOUTK + tid] = acc;
    }
}

extern "C" void kernel_launch(void* const* d_in, const int* in_sizes, int n_in,
                              void* d_out, int out_size, void* d_ws, size_t ws_size,
                              hipStream_t stream)
{
    const float* x    = (const float*)d_in[0];
    const float* encw = (const float*)d_in[1];
    const float* encb = (const float*)d_in[2];
    const float* inw  = (const float*)d_in[3];
    const float* cw   = (const float*)d_in[4];
    const float* cb   = (const float*)d_in[5];
    const float* xpw  = (const float*)d_in[6];
    const float* dtw  = (const float*)d_in[7];
    const float* dtb  = (const float*)d_in[8];
    const float* alog = (const float*)d_in[9];
    const float* Dp   = (const float*)d_in[10];
    const float* opw  = (const float*)d_in[11];
    const float* lng  = (const float*)d_in[12];
    const float* lnb  = (const float*)d_in[13];
    const float* hw   = (const float*)d_in[14];
    const float* hb   = (const float*)d_in[15];
    float* out = (float*)d_out;

    float* ws   = (float*)d_ws;
    float* bc   = ws;                               // BL*32 f32 (B|C)
    float* cS   = bc  + (size_t)BL * 32;            // B*DI*NC f32 (sum dt)
    float* cH   = cS  + (size_t)BB * DI * NC;       // B*DI*NC*16 f32
    float* r16  = cH  + (size_t)BB * DI * NC * DS;  // BL*16 f32
    float* dtwT = r16 + (size_t)BL * 16;            // 2*16*512 f32
    float* hlast = dtwT + 2 * 16 * 512;             // BB*DM f32
    ushort* h_bf    = (ushort*)(hlast + BB * DM);   // BL*256 (residual stream)
    ushort* xz_bf   = h_bf  + (size_t)BL * DM;      // BL*1024
    ushort* xi_bf   = xz_bf + (size_t)BL * 1024;    // BL*512
    ushort* dt_bf   = xi_bf + (size_t)BL * DI;      // BL*512 (softplus'd dt)
    ushort* inw_bf  = dt_bf + (size_t)BL * DI;      // 2*1024*256
    ushort* opw_bf  = inw_bf + 2 * 1024 * DM;       // 2*256*512
    ushort* xpw48_bf = opw_bf + 2 * DM * DI;        // 2*64*512 (rows 48-63 = 0)

    dim3 blk(256, 1, 1);

    prep_enc_kernel<<<dim3(PREP_BLOCKS + ENC_BLOCKS), blk, 0, stream>>>(
        inw, opw, xpw, dtw, inw_bf, opw_bf, xpw48_bf, dtwT,
        x, encw, encb, h_bf);

    for (int l = 0; l < 2; ++l) {
        // in_proj -> xz_bf (bf16 only)
        mfma_gemm<0><<<dim3(1024/128, BL/64), blk, 0, stream>>>(
            h_bf, DM, inw_bf + (size_t)l * 1024 * DM,
            xz_bf, 1024, DM);
        // conv + silu -> xi_bf
        conv_silu_kernel<<<dim3(BL * 128 / 8 / 256), blk, 0, stream>>>(
            xz_bf, cw + l * DI * 4, cb + l * DI, xi_bf);
        // skinny xproj: [r16 | B | C] = xi @ xpw48^T
        mfma_gemm48<<<dim3(1, BL/64), blk, 0, stream>>>(
            xi_bf, xpw48_bf + (size_t)l * 64 * DI, r16, bc);
        // dt = softplus(r16 @ dtw^T + dtb) -> bf16 (via transposed dtwT)
        dt_combine_kernel<<<dim3(BL * 128 / 256), blk, 0, stream>>>(
            r16, dtwT + (size_t)l * 16 * 512, dtb + (size_t)l * DI, dt_bf);
        // scan
        scan_phase1<<<dim3(NC, BB, 2), blk, 0, stream>>>(
            xi_bf, dt_bf, bc, alog + (size_t)l * DI * 16, cS, cH);
        scan_phase2<<<dim3(BB * DI), blk, 0, stream>>>(
            cS, cH, alog + (size_t)l * DI * 16);
        if (l == 0) {
            scan_phase3<<<dim3(NC, BB, 2), blk, 0, stream>>>(
                xz_bf, xi_bf, dt_bf, bc, alog + (size_t)l * DI * 16,
                Dp + l * DI, cH, 0);
            // out_proj with bf16 residual read-modify-write on h_bf
            mfma_gemm<2><<<dim3(DM/128, BL/64), blk, 0, stream>>>(
                xi_bf, DI, opw_bf + (size_t)l * DM * DI,
                h_bf, DM, DI);
        } else {
            scan_phase3<<<dim3(1, BB, 2), blk, 0, stream>>>(
                xz_bf, xi_bf, dt_bf, bc, alog + (size_t)l * DI * 16,
                Dp + l * DI, cH, NC - 1);
            out_proj_last_kernel<<<dim3(BB), blk, 0, stream>>>(
                xi_bf, opw + (size_t)l * DM * DI, h_bf, hlast);
        }
    }

    ln_head_kernel<<<dim3(BB), blk, 0, stream>>>(hlast, lng, lnb, hw, hb, out);
}

// Round 11
// 318.301 us; speedup vs baseline: 1.2575x; 1.0010x over previous
//
#include <hip/hip_runtime.h>
#include <hip/hip_bf16.h>
#include <math.h>

#define BB 4
#define LL 4096
#define DM 256
#define DI 512
#define DS 16
#define NOUTK 128
#define LN_EPS 1e-5f
#define NC 128
#define CLEN (LL/NC)
#define BL (BB*LL)

typedef __attribute__((ext_vector_type(8))) short short8;
typedef __attribute__((ext_vector_type(4))) float f32x4;

__device__ __forceinline__ ushort f2bf(float f) {
    union { float f; unsigned u; } v; v.f = f;
    unsigned r = (v.u + 0x7FFF + ((v.u >> 16) & 1)) >> 16;
    return (ushort)r;
}
__device__ __forceinline__ float bf2f(ushort u) {
    union { unsigned u; float f; } v; v.u = ((unsigned)u) << 16;
    return v.f;
}

// ---------------- fused weight prep + encoder ------------------------------
#define PREP_N1 (2*1024*256)
#define PREP_N2 (2*256*512)
#define PREP_N3 (2*64*512)     /* xpw rows 0..47 cast to bf16, padded to 64 */
#define PREP_N4 (2*16*512)     /* dtw transposed to [k][n], f32 */
#define PREP_BLOCKS ((PREP_N1 + PREP_N2 + PREP_N3 + PREP_N4) / 256)
#define ENC_BLOCKS (BL / 4)
__global__ __launch_bounds__(256) void prep_enc_kernel(
    const float* __restrict__ inw, const float* __restrict__ opw,
    const float* __restrict__ xpw, const float* __restrict__ dtw,
    ushort* __restrict__ inw_bf, ushort* __restrict__ opw_bf,
    ushort* __restrict__ xpw48_bf, float* __restrict__ dtwT,
    const float* __restrict__ x, const float* __restrict__ encw,
    const float* __restrict__ encb, ushort* __restrict__ hbf)
{
    int tid = threadIdx.x;
    if (blockIdx.x < PREP_BLOCKS) {
        int i = blockIdx.x * 256 + tid;
        if (i < PREP_N1) {
            inw_bf[i] = f2bf(inw[i]);
            return;
        }
        int j = i - PREP_N1;
        if (j < PREP_N2) {
            opw_bf[j] = f2bf(opw[j]);
            return;
        }
        int m = j - PREP_N2;
        if (m < PREP_N3) {
            int l = m / (64 * 512);
            int rem = m - l * 64 * 512;
            int row = rem >> 9, k = rem & 511;
            float v = (row < 48) ? xpw[(size_t)l * 48 * 512 + row * 512 + k] : 0.f;
            xpw48_bf[m] = f2bf(v);
            return;
        }
        int m2 = m - PREP_N3;
        if (m2 >= PREP_N4) return;
        int l = m2 / (16 * 512);
        int rem = m2 - l * 16 * 512;
        int k = rem >> 9, n = rem & 511;
        dtwT[m2] = dtw[(size_t)l * 512 * 16 + n * 16 + k];
        return;
    }
    // ---- encoder branch ----
    __shared__ float sw[256 * 33];
    __shared__ float sx[4][32];
    for (int i = tid; i < 256 * 8; i += 256) {
        float4 v = ((const float4*)encw)[i];
        int r = i >> 3, c = (i & 7) * 4;
        sw[r * 33 + c + 0] = v.x; sw[r * 33 + c + 1] = v.y;
        sw[r * 33 + c + 2] = v.z; sw[r * 33 + c + 3] = v.w;
    }
    int row0 = (blockIdx.x - PREP_BLOCKS) * 4;
    if (tid < 32) {
        for (int rr = 0; rr < 4; ++rr)
            sx[rr][tid] = x[(size_t)(row0 + rr) * 32 + tid];
    }
    __syncthreads();
    float bb = encb[tid];
    #pragma unroll
    for (int rr = 0; rr < 4; ++rr) {
        float acc = bb;
        #pragma unroll
        for (int k = 0; k < 32; ++k)
            acc = fmaf(sx[rr][k], sw[tid * 33 + k], acc);
        hbf[(size_t)(row0 + rr) * DM + tid] = f2bf(acc);
    }
}

// ---------------- bf16 MFMA GEMM: C = epi(A @ W^T) -------------------------
// Tile 64(M) x 128(N), 4 waves of 32x64, single-buffered 24 KB LDS
// (m97-style 2-barrier k-loop; latency hidden by co-resident blocks).
// FROZEN CONFIG. Post-mortems:
//  R3: explicit LDS double-buffer (48 KB) -> -31 us (residency 6->3).
//  R5: forced launch_bounds(256,6) -> spill, flat despite traffic cuts.
//  R7: LDS-free direct fragment loads -> 2x SLOWER (each wave load touches
//      16 cache lines; LDS staging IS the coalescing transform here).
// EPI: 0 plain bf16 out; 2 residual bf16 read-modify-write on Cbf.
template<int EPI>
__global__ __launch_bounds__(256, 4) void mfma_gemm(
    const ushort* __restrict__ A, int lda,
    const ushort* __restrict__ W,
    ushort* Cbf, int ldcbf,
    int K)
{
    __shared__ ushort As[64 * 64];
    __shared__ ushort Ws[128 * 64];
    const int tid = threadIdx.x;

    // XCD-aware bijective swizzle (nwg % 8 == 0 for all our launches)
    int nwg = gridDim.x * gridDim.y;
    int wlin = blockIdx.y * gridDim.x + blockIdx.x;
    int gx = blockIdx.x, gy = blockIdx.y;
    if ((nwg & 7) == 0) {
        int q = nwg >> 3;
        int s = (wlin & 7) * q + (wlin >> 3);
        gx = s % gridDim.x;
        gy = s / gridDim.x;
    }
    const int bm = gy * 64;
    const int bn = gx * 128;
    const int wid = tid >> 6, lane = tid & 63;
    const int wrow = (wid >> 1) * 32, wcol = (wid & 1) * 64;
    const int sr = tid >> 3;
    const int sc = tid & 7;

    f32x4 acc[2][4];
    #pragma unroll
    for (int mi = 0; mi < 2; ++mi)
        #pragma unroll
        for (int ni = 0; ni < 4; ++ni)
            acc[mi][ni] = (f32x4){0.f, 0.f, 0.f, 0.f};

    const int nk = K >> 6;          // 4 (K=256) or 8 (K=512)
    for (int t = 0; t < nk; ++t) {
        const int k0 = t << 6;
        #pragma unroll
        for (int it = 0; it < 2; ++it) {
            int r = it * 32 + sr;
            int csrc = sc ^ (r & 7);
            __builtin_amdgcn_global_load_lds(
                (const __attribute__((address_space(1))) unsigned int*)
                    (A + (size_t)(bm + r) * lda + k0 + csrc * 8),
                (__attribute__((address_space(3))) unsigned int*)
                    (As + r * 64 + sc * 8), 16, 0, 0);
        }
        #pragma unroll
        for (int it = 0; it < 4; ++it) {
            int r = it * 32 + sr;
            int csrc = sc ^ (r & 7);
            __builtin_amdgcn_global_load_lds(
                (const __attribute__((address_space(1))) unsigned int*)
                    (W + (size_t)(bn + r) * K + k0 + csrc * 8),
                (__attribute__((address_space(3))) unsigned int*)
                    (Ws + r * 64 + sc * 8), 16, 0, 0);
        }
        __syncthreads();
        #pragma unroll
        for (int kk = 0; kk < 2; ++kk) {
            short8 af[2], bfr[4];
            #pragma unroll
            for (int mi = 0; mi < 2; ++mi) {
                int r = wrow + mi * 16 + (lane & 15);
                int c = (lane >> 4) + kk * 4;
                af[mi] = *(const short8*)(As + r * 64 + ((c ^ (r & 7)) << 3));
            }
            #pragma unroll
            for (int ni = 0; ni < 4; ++ni) {
                int r = wcol + ni * 16 + (lane & 15);
                int c = (lane >> 4) + kk * 4;
                bfr[ni] = *(const short8*)(Ws + r * 64 + ((c ^ (r & 7)) << 3));
            }
            #pragma unroll
            for (int mi = 0; mi < 2; ++mi)
                #pragma unroll
                for (int ni = 0; ni < 4; ++ni)
                    acc[mi][ni] = __builtin_amdgcn_mfma_f32_16x16x32_bf16(
                        af[mi], bfr[ni], acc[mi][ni], 0, 0, 0);
        }
        __syncthreads();
    }

    #pragma unroll
    for (int mi = 0; mi < 2; ++mi)
        #pragma unroll
        for (int ni = 0; ni < 4; ++ni) {
            int col = bn + wcol + ni * 16 + (lane & 15);
            #pragma unroll
            for (int r = 0; r < 4; ++r) {
                int row = bm + wrow + mi * 16 + (lane >> 4) * 4 + r;
                float v = acc[mi][ni][r];
                if (EPI == 2) {
                    size_t o = (size_t)row * ldcbf + col;
                    float vv = v + bf2f(Cbf[o]);
                    Cbf[o] = f2bf(vv);
                } else {
                    Cbf[(size_t)row * ldcbf + col] = f2bf(v);
                }
            }
        }
}

// ---------------- skinny xproj GEMM v2: [r16 | B | C] = xi @ xpw48^T -------
// In-block split-K: 4 waves each own K-slice of 128 (2 k-steps) staged into
// WAVE-PRIVATE LDS buffers -> NO __syncthreads in the k-loop, only a
// wave-level s_waitcnt vmcnt(0) (no cross-wave drain). Serial chain 8 -> 2.
// Then 2 barriers: waves dump partial 64x64 f32 tiles to LDS, 256 threads
// cooperatively sum 4 tiles and write r16/bc.
// (R10 post-mortem: v1 reused the 8-step 2-barrier template at 1 wave/SIMD
//  -> zero TLP, every step paid full latency, ~30 us for 0.8 GFLOP.)
__global__ __launch_bounds__(256) void mfma_gemm48(
    const ushort* __restrict__ A,      // xi_bf, lda = 512
    const ushort* __restrict__ W,      // xpw48_bf layer base: 64 x 512
    float* __restrict__ r16,           // BL x 16 f32
    float* __restrict__ bc)            // BL x 32 f32
{
    __shared__ __align__(16) ushort stage[4][2][64 * 64];   // 64 KB
    const int tid = threadIdx.x;

    int nwg = gridDim.y;               // 256
    int wlin = blockIdx.y;
    int gy = wlin;
    if ((nwg & 7) == 0) {
        int q = nwg >> 3;
        gy = (wlin & 7) * q + (wlin >> 3);
    }
    const int bm = gy * 64;
    const int wid = tid >> 6, lane = tid & 63;

    f32x4 acc[4][4];
    #pragma unroll
    for (int mi = 0; mi < 4; ++mi)
        #pragma unroll
        for (int ni = 0; ni < 4; ++ni)
            acc[mi][ni] = (f32x4){0.f, 0.f, 0.f, 0.f};

    ushort* Aw = &stage[wid][0][0];
    ushort* Ww = &stage[wid][1][0];
    const int k0w = wid * 128;         // this wave's K-slice base

    #pragma unroll
    for (int t = 0; t < 2; ++t) {
        const int k0 = k0w + t * 64;
        #pragma unroll
        for (int it = 0; it < 8; ++it) {
            int r = it * 8 + (lane >> 3);
            int sc = lane & 7;
            int csrc = sc ^ (r & 7);
            __builtin_amdgcn_global_load_lds(
                (const __attribute__((address_space(1))) unsigned int*)
                    (A + (size_t)(bm + r) * DI + k0 + csrc * 8),
                (__attribute__((address_space(3))) unsigned int*)
                    (Aw + r * 64 + sc * 8), 16, 0, 0);
        }
        #pragma unroll
        for (int it = 0; it < 8; ++it) {
            int r = it * 8 + (lane >> 3);
            int sc = lane & 7;
            int csrc = sc ^ (r & 7);
            __builtin_amdgcn_global_load_lds(
                (const __attribute__((address_space(1))) unsigned int*)
                    (W + (size_t)r * DI + k0 + csrc * 8),
                (__attribute__((address_space(3))) unsigned int*)
                    (Ww + r * 64 + sc * 8), 16, 0, 0);
        }
        // wave-private buffers: wave-level wait, no barrier
        asm volatile("s_waitcnt vmcnt(0)" ::: "memory");
        #pragma unroll
        for (int kk = 0; kk < 2; ++kk) {
            short8 af[4], bfr[4];
            #pragma unroll
            for (int mi = 0; mi < 4; ++mi) {
                int r = mi * 16 + (lane & 15);
                int c = (lane >> 4) + kk * 4;
                af[mi] = *(const short8*)(Aw + r * 64 + ((c ^ (r & 7)) << 3));
            }
            #pragma unroll
            for (int ni = 0; ni < 4; ++ni) {
                int r = ni * 16 + (lane & 15);
                int c = (lane >> 4) + kk * 4;
                bfr[ni] = *(const short8*)(Ww + r * 64 + ((c ^ (r & 7)) << 3));
            }
            #pragma unroll
            for (int mi = 0; mi < 4; ++mi)
                #pragma unroll
                for (int ni = 0; ni < 4; ++ni)
                    acc[mi][ni] = __builtin_amdgcn_mfma_f32_16x16x32_bf16(
                        af[mi], bfr[ni], acc[mi][ni], 0, 0, 0);
        }
    }

    // cross-wave reduction: dump partials (reuse staging LDS as f32)
    __syncthreads();
    float* redw = (float*)&stage[wid][0][0];    // 4096 floats per wave
    #pragma unroll
    for (int mi = 0; mi < 4; ++mi)
        #pragma unroll
        for (int ni = 0; ni < 4; ++ni)
            #pragma unroll
            for (int r = 0; r < 4; ++r) {
                int row = mi * 16 + (lane >> 4) * 4 + r;
                int col = ni * 16 + (lane & 15);
                redw[row * 64 + col] = acc[mi][ni][r];
            }
    __syncthreads();
    const float* red0 = (const float*)&stage[0][0][0];
    #pragma unroll
    for (int j = 0; j < 16; ++j) {
        int e = tid + j * 256;                  // conflict-free, coalesced
        int row = e >> 6, col = e & 63;
        float v = red0[e] + red0[4096 + e] + red0[2 * 4096 + e]
                + red0[3 * 4096 + e];
        int grow = bm + row;
        if (col < 16)       r16[(size_t)grow * 16 + col] = v;
        else if (col < 48)  bc[(size_t)grow * 32 + (col - 16)] = v;
    }
}

// ---------------- dt finish: dt = softplus(r16 @ dtw^T + dtb), bf16 --------
// Uses TRANSPOSED dtwT[k][n]: lane i reads dtwT[k][n0..n0+3] -> 64 lanes x
// 16 B = one contiguous 1 KB segment per load (L1-resident). R9's version
// read dtw row-major: 64 distinct cache lines per load -> 69 us stall.
__global__ __launch_bounds__(256) void dt_combine_kernel(
    const float* __restrict__ r16, const float* __restrict__ dtwT,
    const float* __restrict__ dtb, ushort* __restrict__ dt_bf)
{
    int idx = blockIdx.x * 256 + threadIdx.x;   // over BL*128
    int n0 = (idx & 127) * 4;
    int row = idx >> 7;
    const float* rp = r16 + (size_t)row * 16;
    float4 acc = *(const float4*)(dtb + n0);
    #pragma unroll
    for (int k = 0; k < 16; ++k) {
        float rk = rp[k];
        float4 wv = *(const float4*)(dtwT + k * 512 + n0);
        acc.x = fmaf(rk, wv.x, acc.x);
        acc.y = fmaf(rk, wv.y, acc.y);
        acc.z = fmaf(rk, wv.z, acc.z);
        acc.w = fmaf(rk, wv.w, acc.w);
    }
    ushort4 o;
    o.x = f2bf(fmaxf(acc.x, 0.f) + __logf(1.f + __expf(-fabsf(acc.x))));
    o.y = f2bf(fmaxf(acc.y, 0.f) + __logf(1.f + __expf(-fabsf(acc.y))));
    o.z = f2bf(fmaxf(acc.z, 0.f) + __logf(1.f + __expf(-fabsf(acc.z))));
    o.w = f2bf(fmaxf(acc.w, 0.f) + __logf(1.f + __expf(-fabsf(acc.w))));
    *(ushort4*)(dt_bf + (size_t)row * 512 + n0) = o;
}

// ---------------- causal conv (width 4) + bias + silu, bf16 in/out ---------
__global__ __launch_bounds__(256) void conv_silu_kernel(
    const ushort* __restrict__ xz, const float* __restrict__ cw,
    const float* __restrict__ cb, ushort* __restrict__ xi)
{
    int idx = blockIdx.x * 256 + threadIdx.x;   // over (BL/8)*128
    int d4 = (idx & 127) * 4;
    int grp = idx >> 7;                          // 0 .. BL/8-1
    int b = grp >> 9;                            // LL/8 = 512 groups per b
    int t0 = (grp & 511) * 8;
    const ushort* base = xz + ((size_t)(b * LL + t0) * 1024) + d4;
    ushort* obase = xi + ((size_t)(b * LL + t0) * 512) + d4;

    float4 w0 = *(const float4*)(cw + (d4 + 0) * 4);
    float4 w1 = *(const float4*)(cw + (d4 + 1) * 4);
    float4 w2 = *(const float4*)(cw + (d4 + 2) * 4);
    float4 w3 = *(const float4*)(cw + (d4 + 3) * 4);
    float b0 = cb[d4 + 0], b1 = cb[d4 + 1], b2 = cb[d4 + 2], b3 = cb[d4 + 3];

    ushort4 z4 = {0, 0, 0, 0};
    ushort4 win0 = (t0 >= 3) ? *(const ushort4*)(base - 3 * 1024) : z4;
    ushort4 win1 = (t0 >= 2) ? *(const ushort4*)(base - 2 * 1024) : z4;
    ushort4 win2 = (t0 >= 1) ? *(const ushort4*)(base - 1 * 1024) : z4;

    #pragma unroll
    for (int k = 0; k < 8; ++k) {
        ushort4 cur = *(const ushort4*)(base + k * 1024);
        float a0 = b0, a1 = b1, a2 = b2, a3 = b3;
        a0 = fmaf(bf2f(win0.x), w0.x, a0); a1 = fmaf(bf2f(win0.y), w1.x, a1);
        a2 = fmaf(bf2f(win0.z), w2.x, a2); a3 = fmaf(bf2f(win0.w), w3.x, a3);
        a0 = fmaf(bf2f(win1.x), w0.y, a0); a1 = fmaf(bf2f(win1.y), w1.y, a1);
        a2 = fmaf(bf2f(win1.z), w2.y, a2); a3 = fmaf(bf2f(win1.w), w3.y, a3);
        a0 = fmaf(bf2f(win2.x), w0.z, a0); a1 = fmaf(bf2f(win2.y), w1.z, a1);
        a2 = fmaf(bf2f(win2.z), w2.z, a2); a3 = fmaf(bf2f(win2.w), w3.z, a3);
        a0 = fmaf(bf2f(cur.x),  w0.w, a0); a1 = fmaf(bf2f(cur.y),  w1.w, a1);
        a2 = fmaf(bf2f(cur.z),  w2.w, a2); a3 = fmaf(bf2f(cur.w),  w3.w, a3);
        ushort4 o;
        o.x = f2bf(a0 / (1.f + __expf(-a0)));
        o.y = f2bf(a1 / (1.f + __expf(-a1)));
        o.z = f2bf(a2 / (1.f + __expf(-a2)));
        o.w = f2bf(a3 / (1.f + __expf(-a3)));
        *(ushort4*)(obase + k * 512) = o;
        win0 = win1; win1 = win2; win2 = cur;
    }
}

// ---------------- chunked selective scan -----------------------------------
__global__ __launch_bounds__(256) void scan_phase1(
    const ushort* __restrict__ xi, const ushort* __restrict__ dtb,
    const float* __restrict__ bc,
    const float* __restrict__ alog,
    float* __restrict__ cS, float* __restrict__ cH)
{
    int d = blockIdx.z * 256 + threadIdx.x;
    int b = blockIdx.y, c = blockIdx.x;
    float Av[16];
    bool fast = true;
    #pragma unroll
    for (int s = 0; s < 16; ++s) {
        Av[s] = -__expf(alog[d * 16 + s]);
        fast = fast && (fabsf(Av[s] + (float)(s + 1)) < 1e-3f * (s + 1));
    }
    float h[16];
    #pragma unroll
    for (int s = 0; s < 16; ++s) h[s] = 0.f;
    float S = 0.f;
    int t0 = c * CLEN;
    if (fast) {
        for (int t = t0; t < t0 + CLEN; ++t) {
            size_t row = (size_t)b * LL + t;
            float dt = bf2f(dtb[row * 512 + d]);
            float x = bf2f(xi[row * 512 + d]);
            float dtx = dt * x;
            S += dt;
            const float* bp = bc + row * 32;
            float e1 = __expf(-dt);
            float e2=e1*e1, e3=e2*e1, e4=e2*e2, e5=e3*e2, e6=e3*e3, e7=e4*e3, e8=e4*e4;
            float e9=e5*e4, e10=e5*e5, e11=e6*e5, e12=e6*e6, e13=e7*e6, e14=e7*e7, e15=e8*e7, e16=e8*e8;
            float pw[16] = {e1,e2,e3,e4,e5,e6,e7,e8,e9,e10,e11,e12,e13,e14,e15,e16};
            #pragma unroll
            for (int s = 0; s < 16; ++s)
                h[s] = fmaf(pw[s], h[s], dtx * bp[s]);
        }
    } else {
        for (int t = t0; t < t0 + CLEN; ++t) {
            size_t row = (size_t)b * LL + t;
            float dt = bf2f(dtb[row * 512 + d]);
            float x = bf2f(xi[row * 512 + d]);
            float dtx = dt * x;
            S += dt;
            const float* bp = bc + row * 32;
            #pragma unroll
            for (int s = 0; s < 16; ++s) {
                float dA = __expf(dt * Av[s]);
                h[s] = fmaf(dA, h[s], dtx * bp[s]);
            }
        }
    }
    cS[((size_t)b * DI + d) * NC + c] = S;
    size_t base = (((size_t)b * DI + d) * NC + c) * 16;
    #pragma unroll
    for (int q = 0; q < 4; ++q)
        *(float4*)(cH + base + q*4) = *(float4*)&h[q*4];
}

// Parallel chunk-prefix: one block per (b,d); 16 threads per s-value,
// each composing 8 chunks; shfl-scan of affine maps F(x)=Ax+H across the
// 16-lane segment (serial chain 128 -> 8+4+8). Decay a = exp(Av[s]*S).
__global__ __launch_bounds__(256) void scan_phase2(
    const float* __restrict__ cS, float* __restrict__ cH,
    const float* __restrict__ alog)
{
    int bd = blockIdx.x;            // b*DI + d
    int d = bd & (DI - 1);
    int tid = threadIdx.x;
    int s = tid >> 4;               // 0..15
    int g = tid & 15;               // chunk group (8 chunks each)
    float Avs = -__expf(alog[d * 16 + s]);
    size_t sbase = (size_t)bd * NC;
    size_t base = (size_t)bd * NC * 16 + s;
    float a8[8], h8[8];
    #pragma unroll
    for (int j = 0; j < 8; ++j) {
        float Sj = cS[sbase + g * 8 + j];
        a8[j] = __expf(Avs * Sj);
        h8[j] = cH[base + (size_t)(g * 8 + j) * 16];
    }
    float A = 1.f, H = 0.f;
    #pragma unroll
    for (int j = 0; j < 8; ++j) {
        H = fmaf(a8[j], H, h8[j]);
        A *= a8[j];
    }
    #pragma unroll
    for (int off = 1; off < 16; off <<= 1) {
        float Ap = __shfl_up(A, off, 16);
        float Hp = __shfl_up(H, off, 16);
        if (g >= off) { H = fmaf(A, Hp, H); A *= Ap; }
    }
    float init = __shfl_up(H, 1, 16);
    if (g == 0) init = 0.f;
    #pragma unroll
    for (int j = 0; j < 8; ++j) {
        size_t o = base + (size_t)(g * 8 + j) * 16;
        cH[o] = init;
        init = fmaf(a8[j], init, h8[j]);
    }
}

__global__ __launch_bounds__(256) void scan_phase3(
    const ushort* __restrict__ xz,   // bf16, ld 1024; res at cols 512..1023
    ushort* __restrict__ xi,
    const ushort* __restrict__ dtb,
    const float* __restrict__ bc,
    const float* __restrict__ alog,
    const float* __restrict__ Dp,
    const float* __restrict__ cH,
    int c0)
{
    int d = blockIdx.z * 256 + threadIdx.x;
    int b = blockIdx.y;
    int c = blockIdx.x + c0;
    float Av[16];
    bool fast = true;
    #pragma unroll
    for (int s = 0; s < 16; ++s) {
        Av[s] = -__expf(alog[d * 16 + s]);
        fast = fast && (fabsf(Av[s] + (float)(s + 1)) < 1e-3f * (s + 1));
    }
    float h[16];
    size_t cbase = (((size_t)b * DI + d) * NC + c) * 16;
    #pragma unroll
    for (int q = 0; q < 4; ++q)
        *(float4*)&h[q*4] = *(const float4*)(cH + cbase + q*4);
    float Dd = Dp[d];
    int t0 = c * CLEN;
    if (fast) {
        for (int t = t0; t < t0 + CLEN; ++t) {
            size_t row = (size_t)b * LL + t;
            float dt = bf2f(dtb[row * 512 + d]);
            float x = bf2f(xi[row * 512 + d]);
            float dtx = dt * x;
            const float* bp = bc + row * 32;
            const float* cp = bc + row * 32 + 16;
            float e1 = __expf(-dt);
            float e2=e1*e1, e3=e2*e1, e4=e2*e2, e5=e3*e2, e6=e3*e3, e7=e4*e3, e8=e4*e4;
            float e9=e5*e4, e10=e5*e5, e11=e6*e5, e12=e6*e6, e13=e7*e6, e14=e7*e7, e15=e8*e7, e16=e8*e8;
            float pw[16] = {e1,e2,e3,e4,e5,e6,e7,e8,e9,e10,e11,e12,e13,e14,e15,e16};
            float y = 0.f;
            #pragma unroll
            for (int s = 0; s < 16; ++s) {
                h[s] = fmaf(pw[s], h[s], dtx * bp[s]);
                y = fmaf(h[s], cp[s], y);
            }
            float res = bf2f(xz[row * 1024 + 512 + d]);
            float g = (y + x * Dd) * (res / (1.f + __expf(-res)));
            xi[row * 512 + d] = f2bf(g);
        }
    } else {
        for (int t = t0; t < t0 + CLEN; ++t) {
            size_t row = (size_t)b * LL + t;
            float dt = bf2f(dtb[row * 512 + d]);
            float x = bf2f(xi[row * 512 + d]);
            float dtx = dt * x;
            const float* bp = bc + row * 32;
            const float* cp = bc + row * 32 + 16;
            float y = 0.f;
            #pragma unroll
            for (int s = 0; s < 16; ++s) {
                float dA = __expf(dt * Av[s]);
                h[s] = fmaf(dA, h[s], dtx * bp[s]);
                y = fmaf(h[s], cp[s], y);
            }
            float res = bf2f(xz[row * 1024 + 512 + d]);
            float g = (y + x * Dd) * (res / (1.f + __expf(-res)));
            xi[row * 512 + d] = f2bf(g);
        }
    }
}

// ---------------- last-row out_proj (layer 2) ------------------------------
// hlast[b][n] = bf16_resid(h_bf last row) + out_proj(y last row)
__global__ __launch_bounds__(256) void out_proj_last_kernel(
    const ushort* __restrict__ xi, const float* __restrict__ W,
    const ushort* __restrict__ hbf, float* __restrict__ hlast)
{
    int b = blockIdx.x, n = threadIdx.x;
    __shared__ float sy[DI];
    const ushort* yrow = xi + ((size_t)b * LL + (LL - 1)) * DI;
    for (int k = threadIdx.x; k < DI; k += 256) sy[k] = bf2f(yrow[k]);
    __syncthreads();
    const float* wr = W + (size_t)n * DI;
    float acc = 0.f;
    for (int k = 0; k < DI; k += 4) {
        float4 wv = *(const float4*)(wr + k);
        acc = fmaf(sy[k+0], wv.x, acc);
        acc = fmaf(sy[k+1], wv.y, acc);
        acc = fmaf(sy[k+2], wv.z, acc);
        acc = fmaf(sy[k+3], wv.w, acc);
    }
    hlast[b * DM + n] = acc + bf2f(hbf[((size_t)b * LL + (LL - 1)) * DM + n]);
}

// ---------------- final LN (last row only) + head --------------------------
__global__ __launch_bounds__(256) void ln_head_kernel(
    const float* __restrict__ hlast, const float* __restrict__ lng,
    const float* __restrict__ lnb, const float* __restrict__ hw,
    const float* __restrict__ hb, float* __restrict__ out)
{
    int b = blockIdx.x, tid = threadIdx.x;
    __shared__ float sh[DM];
    __shared__ float r1[4], r2[4];
    float v = hlast[b * DM + tid];
    float s = v;
    #pragma unroll
    for (int o = 32; o >= 1; o >>= 1) s += __shfl_down(s, o);
    if ((tid & 63) == 0) r1[tid >> 6] = s;
    __syncthreads();
    float mu = (r1[0] + r1[1] + r1[2] + r1[3]) * (1.f / 256.f);
    float dv = v - mu;
    float q = dv * dv;
    #pragma unroll
    for (int o = 32; o >= 1; o >>= 1) q += __shfl_down(q, o);
    if ((tid & 63) == 0) r2[tid >> 6] = q;
    __syncthreads();
    float var = (r2[0] + r2[1] + r2[2] + r2[3]) * (1.f / 256.f);
    sh[tid] = dv * rsqrtf(var + LN_EPS) * lng[tid] + lnb[tid];
    __syncthreads();
    if (tid < NOUTK) {
        const float* wr = hw + (size_t)tid * DM;
        float acc = hb[tid];
        for (int d2 = 0; d2 < DM; d2 += 4) {
            float4 wv = *(const float4*)(wr + d2);
            acc = fmaf(sh[d2+0], wv.x, acc);
            acc = fmaf(sh[d2+1], wv.y, acc);
            acc = fmaf(sh[d2+2], wv.z, acc);
            acc = fmaf(sh[d2+3], wv.w, acc);
        }
        out[b * NOUTK + tid] = acc;
    }
}

extern "C" void kernel_launch(void* const* d_in, const int* in_sizes, int n_in,
                              void* d_out, int out_size, void* d_ws, size_t ws_size,
                              hipStream_t stream)
{
    const float* x    = (const float*)d_in[0];
    const float* encw = (const float*)d_in[1];
    const float* encb = (const float*)d_in[2];
    const float* inw  = (const float*)d_in[3];
    const float* cw   = (const float*)d_in[4];
    const float* cb   = (const float*)d_in[5];
    const float* xpw  = (const float*)d_in[6];
    const float* dtw  = (const float*)d_in[7];
    const float* dtb  = (const float*)d_in[8];
    const float* alog = (const float*)d_in[9];
    const float* Dp   = (const float*)d_in[10];
    const float* opw  = (const float*)d_in[11];
    const float* lng  = (const float*)d_in[12];
    const float* lnb  = (const float*)d_in[13];
    const float* hw   = (const float*)d_in[14];
    const float* hb   = (const float*)d_in[15];
    float* out = (float*)d_out;

    float* ws   = (float*)d_ws;
    float* bc   = ws;                               // BL*32 f32 (B|C)
    float* cS   = bc  + (size_t)BL * 32;            // B*DI*NC f32 (sum dt)
    float* cH   = cS  + (size_t)BB * DI * NC;       // B*DI*NC*16 f32
    float* r16  = cH  + (size_t)BB * DI * NC * DS;  // BL*16 f32
    float* dtwT = r16 + (size_t)BL * 16;            // 2*16*512 f32
    float* hlast = dtwT + 2 * 16 * 512;             // BB*DM f32
    ushort* h_bf    = (ushort*)(hlast + BB * DM);   // BL*256 (residual stream)
    ushort* xz_bf   = h_bf  + (size_t)BL * DM;      // BL*1024
    ushort* xi_bf   = xz_bf + (size_t)BL * 1024;    // BL*512
    ushort* dt_bf   = xi_bf + (size_t)BL * DI;      // BL*512 (softplus'd dt)
    ushort* inw_bf  = dt_bf + (size_t)BL * DI;      // 2*1024*256
    ushort* opw_bf  = inw_bf + 2 * 1024 * DM;       // 2*256*512
    ushort* xpw48_bf = opw_bf + 2 * DM * DI;        // 2*64*512 (rows 48-63 = 0)

    dim3 blk(256, 1, 1);

    prep_enc_kernel<<<dim3(PREP_BLOCKS + ENC_BLOCKS), blk, 0, stream>>>(
        inw, opw, xpw, dtw, inw_bf, opw_bf, xpw48_bf, dtwT,
        x, encw, encb, h_bf);

    for (int l = 0; l < 2; ++l) {
        // in_proj -> xz_bf (bf16 only)
        mfma_gemm<0><<<dim3(1024/128, BL/64), blk, 0, stream>>>(
            h_bf, DM, inw_bf + (size_t)l * 1024 * DM,
            xz_bf, 1024, DM);
        // conv + silu -> xi_bf
        conv_silu_kernel<<<dim3(BL * 128 / 8 / 256), blk, 0, stream>>>(
            xz_bf, cw + l * DI * 4, cb + l * DI, xi_bf);
        // skinny xproj v2: [r16 | B | C] = xi @ xpw48^T (split-K in block)
        mfma_gemm48<<<dim3(1, BL/64), blk, 0, stream>>>(
            xi_bf, xpw48_bf + (size_t)l * 64 * DI, r16, bc);
        // dt = softplus(r16 @ dtw^T + dtb) -> bf16 (via transposed dtwT)
        dt_combine_kernel<<<dim3(BL * 128 / 256), blk, 0, stream>>>(
            r16, dtwT + (size_t)l * 16 * 512, dtb + (size_t)l * DI, dt_bf);
        // scan
        scan_phase1<<<dim3(NC, BB, 2), blk, 0, stream>>>(
            xi_bf, dt_bf, bc, alog + (size_t)l * DI * 16, cS, cH);
        scan_phase2<<<dim3(BB * DI), blk, 0, stream>>>(
            cS, cH, alog + (size_t)l * DI * 16);
        if (l == 0) {
            scan_phase3<<<dim3(NC, BB, 2), blk, 0, stream>>>(
                xz_bf, xi_bf, dt_bf, bc, alog + (size_t)l * DI * 16,
                Dp + l * DI, cH, 0);
            // out_proj with bf16 residual read-modify-write on h_bf
            mfma_gemm<2><<<dim3(DM/128, BL/64), blk, 0, stream>>>(
                xi_bf, DI, opw_bf + (size_t)l * DM * DI,
                h_bf, DM, DI);
        } else {
            scan_phase3<<<dim3(1, BB, 2), blk, 0, stream>>>(
                xz_bf, xi_bf, dt_bf, bc, alog + (size_t)l * DI * 16,
                Dp + l * DI, cH, NC - 1);
            out_proj_last_kernel<<<dim3(BB), blk, 0, stream>>>(
                xi_bf, opw + (size_t)l * DM * DI, h_bf, hlast);
        }
    }

    ln_head_kernel<<<dim3(BB), blk, 0, stream>>>(hlast, lng, lnb, hw, hb, out);
}

// Round 12
// 311.947 us; speedup vs baseline: 1.2832x; 1.0204x over previous
//
#include <hip/hip_runtime.h>
#include <hip/hip_bf16.h>
#include <math.h>

#define BB 4
#define LL 4096
#define DM 256
#define DI 512
#define DS 16
#define NOUTK 128
#define LN_EPS 1e-5f
#define NC 128
#define CLEN (LL/NC)
#define BL (BB*LL)
#define LDB 640

typedef __attribute__((ext_vector_type(8))) short short8;
typedef __attribute__((ext_vector_type(4))) float f32x4;

__device__ __forceinline__ ushort f2bf(float f) {
    union { float f; unsigned u; } v; v.f = f;
    unsigned r = (v.u + 0x7FFF + ((v.u >> 16) & 1)) >> 16;
    return (ushort)r;
}
__device__ __forceinline__ float bf2f(ushort u) {
    union { unsigned u; float f; } v; v.u = ((unsigned)u) << 16;
    return v.f;
}

// ---------------- fused weight prep + encoder (R8 form) --------------------
// comb: rows [0,512) = dtw @ xpw[:16] (fused dtproj); [512,544) = B,C rows;
//       [544,640) = 0.
#define PREP_N1 (2*1024*256)
#define PREP_N2 (2*256*512)
#define PREP_N3 (2*640*512)
#define PREP_BLOCKS ((PREP_N1 + PREP_N2 + PREP_N3) / 256)
#define ENC_BLOCKS (BL / 4)
__global__ __launch_bounds__(256) void prep_enc_kernel(
    const float* __restrict__ inw, const float* __restrict__ opw,
    const float* __restrict__ xpw, const float* __restrict__ dtw,
    ushort* __restrict__ inw_bf, ushort* __restrict__ opw_bf,
    ushort* __restrict__ comb_bf,
    const float* __restrict__ x, const float* __restrict__ encw,
    const float* __restrict__ encb, ushort* __restrict__ hbf)
{
    int tid = threadIdx.x;
    if (blockIdx.x < PREP_BLOCKS) {
        int i = blockIdx.x * 256 + tid;
        if (i < PREP_N1) {
            inw_bf[i] = f2bf(inw[i]);
            return;
        }
        int j = i - PREP_N1;
        if (j < PREP_N2) {
            opw_bf[j] = f2bf(opw[j]);
            return;
        }
        int m = j - PREP_N2;
        if (m >= PREP_N3) return;
        int l = m / (640 * 512);
        int rem = m - l * 640 * 512;
        int row = rem >> 9, k = rem & 511;
        const float* xp = xpw + l * 48 * 512;
        const float* dw = dtw + l * 512 * 16;
        float v;
        if (row < 512) {
            v = 0.f;
            #pragma unroll
            for (int r = 0; r < 16; ++r)
                v = fmaf(dw[row * 16 + r], xp[r * 512 + k], v);
        } else if (row < 544) {
            v = xp[(row - 512 + 16) * 512 + k];
        } else v = 0.f;
        comb_bf[m] = f2bf(v);
        return;
    }
    // ---- encoder branch ----
    __shared__ float sw[256 * 33];
    __shared__ float sx[4][32];
    for (int i = tid; i < 256 * 8; i += 256) {
        float4 v = ((const float4*)encw)[i];
        int r = i >> 3, c = (i & 7) * 4;
        sw[r * 33 + c + 0] = v.x; sw[r * 33 + c + 1] = v.y;
        sw[r * 33 + c + 2] = v.z; sw[r * 33 + c + 3] = v.w;
    }
    int row0 = (blockIdx.x - PREP_BLOCKS) * 4;
    if (tid < 32) {
        for (int rr = 0; rr < 4; ++rr)
            sx[rr][tid] = x[(size_t)(row0 + rr) * 32 + tid];
    }
    __syncthreads();
    float bb = encb[tid];
    #pragma unroll
    for (int rr = 0; rr < 4; ++rr) {
        float acc = bb;
        #pragma unroll
        for (int k = 0; k < 32; ++k)
            acc = fmaf(sx[rr][k], sw[tid * 33 + k], acc);
        hbf[(size_t)(row0 + rr) * DM + tid] = f2bf(acc);
    }
}

// ---------------- bf16 MFMA GEMM: C = epi(A @ W^T) -------------------------
// Tile 32(M) x 128(N), 4 waves of 16x64, single-buffered 20 KB LDS
// (m97-style 2-barrier k-loop; latency hidden by co-resident blocks).
// R12: M-tile 64->32 (parameter change within the proven template, like
// R2's winning 128->64): LDS 24->20 KB (8 blocks/CU cap, was 6), acc VGPR
// 32->16, block count 2x (out_proj 2->4 blocks/CU). Same math order.
// Structural experiments all failed and stay out:
//  R3: explicit LDS double-buffer (48 KB) -> -31 us (residency 6->3).
//  R5: forced launch_bounds(256,6) -> spill, flat despite traffic cuts.
//  R7: LDS-free direct fragment loads -> 2x SLOWER (each wave load touches
//      16 cache lines; LDS staging IS the coalescing transform here).
//  R9-R11: rank-16 xproj factorization -> net +11 us vs fused; reverted.
// EPI: 0 plain bf16 out; 1 combined-xproj (dt softplus->bf16, B/C->f32 bc);
//      2 residual bf16 read-modify-write on Cbf.
template<int EPI>
__global__ __launch_bounds__(256, 4) void mfma_gemm(
    const ushort* __restrict__ A, int lda,
    const ushort* __restrict__ W,
    const float* __restrict__ bias,
    float* __restrict__ C, int ldc,
    ushort* Cbf, int ldcbf,
    int K)
{
    __shared__ ushort As[32 * 64];
    __shared__ ushort Ws[128 * 64];
    const int tid = threadIdx.x;

    // XCD-aware bijective swizzle (nwg % 8 == 0 for all our launches)
    int nwg = gridDim.x * gridDim.y;
    int wlin = blockIdx.y * gridDim.x + blockIdx.x;
    int gx = blockIdx.x, gy = blockIdx.y;
    if ((nwg & 7) == 0) {
        int q = nwg >> 3;
        int s = (wlin & 7) * q + (wlin >> 3);
        gx = s % gridDim.x;
        gy = s / gridDim.x;
    }
    const int bm = gy * 32;
    const int bn = gx * 128;
    const int wid = tid >> 6, lane = tid & 63;
    const int wrow = (wid >> 1) * 16, wcol = (wid & 1) * 64;
    const int sr = tid >> 3;            // 0..31
    const int sc = tid & 7;

    f32x4 acc[4];
    #pragma unroll
    for (int ni = 0; ni < 4; ++ni)
        acc[ni] = (f32x4){0.f, 0.f, 0.f, 0.f};

    const int nk = K >> 6;          // 4 (K=256) or 8 (K=512)
    for (int t = 0; t < nk; ++t) {
        const int k0 = t << 6;
        {   // A: 32 rows x 64 cols, one shot (256 threads x 16B)
            int r = sr;
            int csrc = sc ^ (r & 7);
            __builtin_amdgcn_global_load_lds(
                (const __attribute__((address_space(1))) unsigned int*)
                    (A + (size_t)(bm + r) * lda + k0 + csrc * 8),
                (__attribute__((address_space(3))) unsigned int*)
                    (As + r * 64 + sc * 8), 16, 0, 0);
        }
        #pragma unroll
        for (int it = 0; it < 4; ++it) {
            int r = it * 32 + sr;
            int csrc = sc ^ (r & 7);
            __builtin_amdgcn_global_load_lds(
                (const __attribute__((address_space(1))) unsigned int*)
                    (W + (size_t)(bn + r) * K + k0 + csrc * 8),
                (__attribute__((address_space(3))) unsigned int*)
                    (Ws + r * 64 + sc * 8), 16, 0, 0);
        }
        __syncthreads();
        #pragma unroll
        for (int kk = 0; kk < 2; ++kk) {
            short8 af, bfr[4];
            {
                int r = wrow + (lane & 15);
                int c = (lane >> 4) + kk * 4;
                af = *(const short8*)(As + r * 64 + ((c ^ (r & 7)) << 3));
            }
            #pragma unroll
            for (int ni = 0; ni < 4; ++ni) {
                int r = wcol + ni * 16 + (lane & 15);
                int c = (lane >> 4) + kk * 4;
                bfr[ni] = *(const short8*)(Ws + r * 64 + ((c ^ (r & 7)) << 3));
            }
            #pragma unroll
            for (int ni = 0; ni < 4; ++ni)
                acc[ni] = __builtin_amdgcn_mfma_f32_16x16x32_bf16(
                    af, bfr[ni], acc[ni], 0, 0, 0);
        }
        __syncthreads();
    }

    #pragma unroll
    for (int ni = 0; ni < 4; ++ni) {
        int col = bn + wcol + ni * 16 + (lane & 15);
        #pragma unroll
        for (int r = 0; r < 4; ++r) {
            int row = bm + wrow + (lane >> 4) * 4 + r;
            float v = acc[ni][r];
            if (EPI == 1) {
                if (col < 512) {
                    float u = v + bias[col];
                    float sp = fmaxf(u, 0.f) + __logf(1.f + __expf(-fabsf(u)));
                    Cbf[(size_t)row * ldcbf + col] = f2bf(sp);
                } else if (col < 544) {
                    C[(size_t)row * ldc + (col - 512)] = v;
                }
            } else if (EPI == 2) {
                size_t o = (size_t)row * ldcbf + col;
                float vv = v + bf2f(Cbf[o]);
                Cbf[o] = f2bf(vv);
            } else {
                Cbf[(size_t)row * ldcbf + col] = f2bf(v);
            }
        }
    }
}

// ---------------- causal conv (width 4) + bias + silu, bf16 in/out ---------
__global__ __launch_bounds__(256) void conv_silu_kernel(
    const ushort* __restrict__ xz, const float* __restrict__ cw,
    const float* __restrict__ cb, ushort* __restrict__ xi)
{
    int idx = blockIdx.x * 256 + threadIdx.x;   // over (BL/8)*128
    int d4 = (idx & 127) * 4;
    int grp = idx >> 7;                          // 0 .. BL/8-1
    int b = grp >> 9;                            // LL/8 = 512 groups per b
    int t0 = (grp & 511) * 8;
    const ushort* base = xz + ((size_t)(b * LL + t0) * 1024) + d4;
    ushort* obase = xi + ((size_t)(b * LL + t0) * 512) + d4;

    float4 w0 = *(const float4*)(cw + (d4 + 0) * 4);
    float4 w1 = *(const float4*)(cw + (d4 + 1) * 4);
    float4 w2 = *(const float4*)(cw + (d4 + 2) * 4);
    float4 w3 = *(const float4*)(cw + (d4 + 3) * 4);
    float b0 = cb[d4 + 0], b1 = cb[d4 + 1], b2 = cb[d4 + 2], b3 = cb[d4 + 3];

    ushort4 z4 = {0, 0, 0, 0};
    ushort4 win0 = (t0 >= 3) ? *(const ushort4*)(base - 3 * 1024) : z4;
    ushort4 win1 = (t0 >= 2) ? *(const ushort4*)(base - 2 * 1024) : z4;
    ushort4 win2 = (t0 >= 1) ? *(const ushort4*)(base - 1 * 1024) : z4;

    #pragma unroll
    for (int k = 0; k < 8; ++k) {
        ushort4 cur = *(const ushort4*)(base + k * 1024);
        float a0 = b0, a1 = b1, a2 = b2, a3 = b3;
        a0 = fmaf(bf2f(win0.x), w0.x, a0); a1 = fmaf(bf2f(win0.y), w1.x, a1);
        a2 = fmaf(bf2f(win0.z), w2.x, a2); a3 = fmaf(bf2f(win0.w), w3.x, a3);
        a0 = fmaf(bf2f(win1.x), w0.y, a0); a1 = fmaf(bf2f(win1.y), w1.y, a1);
        a2 = fmaf(bf2f(win1.z), w2.y, a2); a3 = fmaf(bf2f(win1.w), w3.y, a3);
        a0 = fmaf(bf2f(win2.x), w0.z, a0); a1 = fmaf(bf2f(win2.y), w1.z, a1);
        a2 = fmaf(bf2f(win2.z), w2.z, a2); a3 = fmaf(bf2f(win2.w), w3.z, a3);
        a0 = fmaf(bf2f(cur.x),  w0.w, a0); a1 = fmaf(bf2f(cur.y),  w1.w, a1);
        a2 = fmaf(bf2f(cur.z),  w2.w, a2); a3 = fmaf(bf2f(cur.w),  w3.w, a3);
        ushort4 o;
        o.x = f2bf(a0 / (1.f + __expf(-a0)));
        o.y = f2bf(a1 / (1.f + __expf(-a1)));
        o.z = f2bf(a2 / (1.f + __expf(-a2)));
        o.w = f2bf(a3 / (1.f + __expf(-a3)));
        *(ushort4*)(obase + k * 512) = o;
        win0 = win1; win1 = win2; win2 = cur;
    }
}

// ---------------- chunked selective scan -----------------------------------
__global__ __launch_bounds__(256) void scan_phase1(
    const ushort* __restrict__ xi, const ushort* __restrict__ dtb,
    const float* __restrict__ bc,
    const float* __restrict__ alog,
    float* __restrict__ cS, float* __restrict__ cH)
{
    int d = blockIdx.z * 256 + threadIdx.x;
    int b = blockIdx.y, c = blockIdx.x;
    float Av[16];
    bool fast = true;
    #pragma unroll
    for (int s = 0; s < 16; ++s) {
        Av[s] = -__expf(alog[d * 16 + s]);
        fast = fast && (fabsf(Av[s] + (float)(s + 1)) < 1e-3f * (s + 1));
    }
    float h[16];
    #pragma unroll
    for (int s = 0; s < 16; ++s) h[s] = 0.f;
    float S = 0.f;
    int t0 = c * CLEN;
    if (fast) {
        for (int t = t0; t < t0 + CLEN; ++t) {
            size_t row = (size_t)b * LL + t;
            float dt = bf2f(dtb[row * 512 + d]);
            float x = bf2f(xi[row * 512 + d]);
            float dtx = dt * x;
            S += dt;
            const float* bp = bc + row * 32;
            float e1 = __expf(-dt);
            float e2=e1*e1, e3=e2*e1, e4=e2*e2, e5=e3*e2, e6=e3*e3, e7=e4*e3, e8=e4*e4;
            float e9=e5*e4, e10=e5*e5, e11=e6*e5, e12=e6*e6, e13=e7*e6, e14=e7*e7, e15=e8*e7, e16=e8*e8;
            float pw[16] = {e1,e2,e3,e4,e5,e6,e7,e8,e9,e10,e11,e12,e13,e14,e15,e16};
            #pragma unroll
            for (int s = 0; s < 16; ++s)
                h[s] = fmaf(pw[s], h[s], dtx * bp[s]);
        }
    } else {
        for (int t = t0; t < t0 + CLEN; ++t) {
            size_t row = (size_t)b * LL + t;
            float dt = bf2f(dtb[row * 512 + d]);
            float x = bf2f(xi[row * 512 + d]);
            float dtx = dt * x;
            S += dt;
            const float* bp = bc + row * 32;
            #pragma unroll
            for (int s = 0; s < 16; ++s) {
                float dA = __expf(dt * Av[s]);
                h[s] = fmaf(dA, h[s], dtx * bp[s]);
            }
        }
    }
    cS[((size_t)b * DI + d) * NC + c] = S;
    size_t base = (((size_t)b * DI + d) * NC + c) * 16;
    #pragma unroll
    for (int q = 0; q < 4; ++q)
        *(float4*)(cH + base + q*4) = *(float4*)&h[q*4];
}

// Parallel chunk-prefix: one block per (b,d); 16 threads per s-value,
// each composing 8 chunks; shfl-scan of affine maps F(x)=Ax+H across the
// 16-lane segment (serial chain 128 -> 8+4+8). Decay a = exp(Av[s]*S).
__global__ __launch_bounds__(256) void scan_phase2(
    const float* __restrict__ cS, float* __restrict__ cH,
    const float* __restrict__ alog)
{
    int bd = blockIdx.x;            // b*DI + d
    int d = bd & (DI - 1);
    int tid = threadIdx.x;
    int s = tid >> 4;               // 0..15
    int g = tid & 15;               // chunk group (8 chunks each)
    float Avs = -__expf(alog[d * 16 + s]);
    size_t sbase = (size_t)bd * NC;
    size_t base = (size_t)bd * NC * 16 + s;
    float a8[8], h8[8];
    #pragma unroll
    for (int j = 0; j < 8; ++j) {
        float Sj = cS[sbase + g * 8 + j];
        a8[j] = __expf(Avs * Sj);
        h8[j] = cH[base + (size_t)(g * 8 + j) * 16];
    }
    float A = 1.f, H = 0.f;
    #pragma unroll
    for (int j = 0; j < 8; ++j) {
        H = fmaf(a8[j], H, h8[j]);
        A *= a8[j];
    }
    #pragma unroll
    for (int off = 1; off < 16; off <<= 1) {
        float Ap = __shfl_up(A, off, 16);
        float Hp = __shfl_up(H, off, 16);
        if (g >= off) { H = fmaf(A, Hp, H); A *= Ap; }
    }
    float init = __shfl_up(H, 1, 16);
    if (g == 0) init = 0.f;
    #pragma unroll
    for (int j = 0; j < 8; ++j) {
        size_t o = base + (size_t)(g * 8 + j) * 16;
        cH[o] = init;
        init = fmaf(a8[j], init, h8[j]);
    }
}

__global__ __launch_bounds__(256) void scan_phase3(
    const ushort* __restrict__ xz,   // bf16, ld 1024; res at cols 512..1023
    ushort* __restrict__ xi,
    const ushort* __restrict__ dtb,
    const float* __restrict__ bc,
    const float* __restrict__ alog,
    const float* __restrict__ Dp,
    const float* __restrict__ cH,
    int c0)
{
    int d = blockIdx.z * 256 + threadIdx.x;
    int b = blockIdx.y;
    int c = blockIdx.x + c0;
    float Av[16];
    bool fast = true;
    #pragma unroll
    for (int s = 0; s < 16; ++s) {
        Av[s] = -__expf(alog[d * 16 + s]);
        fast = fast && (fabsf(Av[s] + (float)(s + 1)) < 1e-3f * (s + 1));
    }
    float h[16];
    size_t cbase = (((size_t)b * DI + d) * NC + c) * 16;
    #pragma unroll
    for (int q = 0; q < 4; ++q)
        *(float4*)&h[q*4] = *(const float4*)(cH + cbase + q*4);
    float Dd = Dp[d];
    int t0 = c * CLEN;
    if (fast) {
        for (int t = t0; t < t0 + CLEN; ++t) {
            size_t row = (size_t)b * LL + t;
            float dt = bf2f(dtb[row * 512 + d]);
            float x = bf2f(xi[row * 512 + d]);
            float dtx = dt * x;
            const float* bp = bc + row * 32;
            const float* cp = bc + row * 32 + 16;
            float e1 = __expf(-dt);
            float e2=e1*e1, e3=e2*e1, e4=e2*e2, e5=e3*e2, e6=e3*e3, e7=e4*e3, e8=e4*e4;
            float e9=e5*e4, e10=e5*e5, e11=e6*e5, e12=e6*e6, e13=e7*e6, e14=e7*e7, e15=e8*e7, e16=e8*e8;
            float pw[16] = {e1,e2,e3,e4,e5,e6,e7,e8,e9,e10,e11,e12,e13,e14,e15,e16};
            float y = 0.f;
            #pragma unroll
            for (int s = 0; s < 16; ++s) {
                h[s] = fmaf(pw[s], h[s], dtx * bp[s]);
                y = fmaf(h[s], cp[s], y);
            }
            float res = bf2f(xz[row * 1024 + 512 + d]);
            float g = (y + x * Dd) * (res / (1.f + __expf(-res)));
            xi[row * 512 + d] = f2bf(g);
        }
    } else {
        for (int t = t0; t < t0 + CLEN; ++t) {
            size_t row = (size_t)b * LL + t;
            float dt = bf2f(dtb[row * 512 + d]);
            float x = bf2f(xi[row * 512 + d]);
            float dtx = dt * x;
            const float* bp = bc + row * 32;
            const float* cp = bc + row * 32 + 16;
            float y = 0.f;
            #pragma unroll
            for (int s = 0; s < 16; ++s) {
                float dA = __expf(dt * Av[s]);
                h[s] = fmaf(dA, h[s], dtx * bp[s]);
                y = fmaf(h[s], cp[s], y);
            }
            float res = bf2f(xz[row * 1024 + 512 + d]);
            float g = (y + x * Dd) * (res / (1.f + __expf(-res)));
            xi[row * 512 + d] = f2bf(g);
        }
    }
}

// ---------------- last-row out_proj (layer 2) ------------------------------
// hlast[b][n] = bf16_resid(h_bf last row) + out_proj(y last row)
__global__ __launch_bounds__(256) void out_proj_last_kernel(
    const ushort* __restrict__ xi, const float* __restrict__ W,
    const ushort* __restrict__ hbf, float* __restrict__ hlast)
{
    int b = blockIdx.x, n = threadIdx.x;
    __shared__ float sy[DI];
    const ushort* yrow = xi + ((size_t)b * LL + (LL - 1)) * DI;
    for (int k = threadIdx.x; k < DI; k += 256) sy[k] = bf2f(yrow[k]);
    __syncthreads();
    const float* wr = W + (size_t)n * DI;
    float acc = 0.f;
    for (int k = 0; k < DI; k += 4) {
        float4 wv = *(const float4*)(wr + k);
        acc = fmaf(sy[k+0], wv.x, acc);
        acc = fmaf(sy[k+1], wv.y, acc);
        acc = fmaf(sy[k+2], wv.z, acc);
        acc = fmaf(sy[k+3], wv.w, acc);
    }
    hlast[b * DM + n] = acc + bf2f(hbf[((size_t)b * LL + (LL - 1)) * DM + n]);
}

// ---------------- final LN (last row only) + head --------------------------
__global__ __launch_bounds__(256) void ln_head_kernel(
    const float* __restrict__ hlast, const float* __restrict__ lng,
    const float* __restrict__ lnb, const float* __restrict__ hw,
    const float* __restrict__ hb, float* __restrict__ out)
{
    int b = blockIdx.x, tid = threadIdx.x;
    __shared__ float sh[DM];
    __shared__ float r1[4], r2[4];
    float v = hlast[b * DM + tid];
    float s = v;
    #pragma unroll
    for (int o = 32; o >= 1; o >>= 1) s += __shfl_down(s, o);
    if ((tid & 63) == 0) r1[tid >> 6] = s;
    __syncthreads();
    float mu = (r1[0] + r1[1] + r1[2] + r1[3]) * (1.f / 256.f);
    float dv = v - mu;
    float q = dv * dv;
    #pragma unroll
    for (int o = 32; o >= 1; o >>= 1) q += __shfl_down(q, o);
    if ((tid & 63) == 0) r2[tid >> 6] = q;
    __syncthreads();
    float var = (r2[0] + r2[1] + r2[2] + r2[3]) * (1.f / 256.f);
    sh[tid] = dv * rsqrtf(var + LN_EPS) * lng[tid] + lnb[tid];
    __syncthreads();
    if (tid < NOUTK) {
        const float* wr = hw + (size_t)tid * DM;
        float acc = hb[tid];
        for (int d2 = 0; d2 < DM; d2 += 4) {
            float4 wv = *(const float4*)(wr + d2);
            acc = fmaf(sh[d2+0], wv.x, acc);
            acc = fmaf(sh[d2+1], wv.y, acc);
            acc = fmaf(sh[d2+2], wv.z, acc);
            acc = fmaf(sh[d2+3], wv.w, acc);
        }
        out[b * NOUTK + tid] = acc;
    }
}

extern "C" void kernel_launch(void* const* d_in, const int* in_sizes, int n_in,
                              void* d_out, int out_size, void* d_ws, size_t ws_size,
                              hipStream_t stream)
{
    const float* x    = (const float*)d_in[0];
    const float* encw = (const float*)d_in[1];
    const float* encb = (const float*)d_in[2];
    const float* inw  = (const float*)d_in[3];
    const float* cw   = (const float*)d_in[4];
    const float* cb   = (const float*)d_in[5];
    const float* xpw  = (const float*)d_in[6];
    const float* dtw  = (const float*)d_in[7];
    const float* dtb  = (const float*)d_in[8];
    const float* alog = (const float*)d_in[9];
    const float* Dp   = (const float*)d_in[10];
    const float* opw  = (const float*)d_in[11];
    const float* lng  = (const float*)d_in[12];
    const float* lnb  = (const float*)d_in[13];
    const float* hw   = (const float*)d_in[14];
    const float* hb   = (const float*)d_in[15];
    float* out = (float*)d_out;

    float* ws   = (float*)d_ws;
    float* bc   = ws;                               // BL*32 f32 (B|C)
    float* cS   = bc  + (size_t)BL * 32;            // B*DI*NC f32 (sum dt)
    float* cH   = cS  + (size_t)BB * DI * NC;       // B*DI*NC*16 f32
    float* hlast = cH + (size_t)BB * DI * NC * DS;  // BB*DM f32
    ushort* h_bf    = (ushort*)(hlast + BB * DM);   // BL*256 (residual stream)
    ushort* xz_bf   = h_bf  + (size_t)BL * DM;      // BL*1024
    ushort* xi_bf   = xz_bf + (size_t)BL * 1024;    // BL*512
    ushort* dt_bf   = xi_bf + (size_t)BL * DI;      // BL*512 (softplus'd dt)
    ushort* inw_bf  = dt_bf + (size_t)BL * DI;      // 2*1024*256
    ushort* opw_bf  = inw_bf + 2 * 1024 * DM;       // 2*256*512
    ushort* comb_bf = opw_bf + 2 * DM * DI;         // 2*640*512

    dim3 blk(256, 1, 1);

    prep_enc_kernel<<<dim3(PREP_BLOCKS + ENC_BLOCKS), blk, 0, stream>>>(
        inw, opw, xpw, dtw, inw_bf, opw_bf, comb_bf,
        x, encw, encb, h_bf);

    for (int l = 0; l < 2; ++l) {
        // in_proj -> xz_bf (bf16 only)
        mfma_gemm<0><<<dim3(1024/128, BL/32), blk, 0, stream>>>(
            h_bf, DM, inw_bf + (size_t)l * 1024 * DM, nullptr,
            nullptr, 0, xz_bf, 1024, DM);
        // conv + silu -> xi_bf
        conv_silu_kernel<<<dim3(BL * 128 / 8 / 256), blk, 0, stream>>>(
            xz_bf, cw + l * DI * 4, cb + l * DI, xi_bf);
        // combined xproj+dtproj: dt_bf = bf16(softplus(xi@Wdt^T + dtb)),
        // bc = f32 [B|C]
        mfma_gemm<1><<<dim3(LDB/128, BL/32), blk, 0, stream>>>(
            xi_bf, DI, comb_bf + (size_t)l * LDB * DI, dtb + l * DI,
            bc, 32, dt_bf, 512, DI);
        // scan
        scan_phase1<<<dim3(NC, BB, 2), blk, 0, stream>>>(
            xi_bf, dt_bf, bc, alog + (size_t)l * DI * 16, cS, cH);
        scan_phase2<<<dim3(BB * DI), blk, 0, stream>>>(
            cS, cH, alog + (size_t)l * DI * 16);
        if (l == 0) {
            scan_phase3<<<dim3(NC, BB, 2), blk, 0, stream>>>(
                xz_bf, xi_bf, dt_bf, bc, alog + (size_t)l * DI * 16,
                Dp + l * DI, cH, 0);
            // out_proj with bf16 residual read-modify-write on h_bf
            mfma_gemm<2><<<dim3(DM/128, BL/32), blk, 0, stream>>>(
                xi_bf, DI, opw_bf + (size_t)l * DM * DI, nullptr,
                nullptr, 0, h_bf, DM, DI);
        } else {
            scan_phase3<<<dim3(1, BB, 2), blk, 0, stream>>>(
                xz_bf, xi_bf, dt_bf, bc, alog + (size_t)l * DI * 16,
                Dp + l * DI, cH, NC - 1);
            out_proj_last_kernel<<<dim3(BB), blk, 0, stream>>>(
                xi_bf, opw + (size_t)l * DM * DI, h_bf, hlast);
        }
    }

    ln_head_kernel<<<dim3(BB), blk, 0, stream>>>(hlast, lng, lnb, hw, hb, out);
}

// Round 13
// 304.847 us; speedup vs baseline: 1.3130x; 1.0233x over previous
//
#include <hip/hip_runtime.h>
#include <hip/hip_bf16.h>
#include <math.h>

#define BB 4
#define LL 4096
#define DM 256
#define DI 512
#define DS 16
#define NOUTK 128
#define LN_EPS 1e-5f
#define NC 128
#define CLEN (LL/NC)
#define BL (BB*LL)
#define LDB 640

typedef __attribute__((ext_vector_type(8))) short short8;
typedef __attribute__((ext_vector_type(8))) ushort ushort8;
typedef __attribute__((ext_vector_type(4))) float f32x4;

__device__ __forceinline__ ushort f2bf(float f) {
    union { float f; unsigned u; } v; v.f = f;
    unsigned r = (v.u + 0x7FFF + ((v.u >> 16) & 1)) >> 16;
    return (ushort)r;
}
__device__ __forceinline__ float bf2f(ushort u) {
    union { unsigned u; float f; } v; v.u = ((unsigned)u) << 16;
    return v.f;
}

// ---------------- fused weight prep + encoder ------------------------------
// comb: rows [0,512) = dtw @ xpw[:16] (fused dtproj); [512,544) = B,C rows;
//       [544,640) = 0.
#define PREP_N1 (2*1024*256)
#define PREP_N2 (2*256*512)
#define PREP_N3 (2*640*512)
#define PREP_BLOCKS ((PREP_N1 + PREP_N2 + PREP_N3) / 256)
#define ENC_BLOCKS (BL / 4)
__global__ __launch_bounds__(256) void prep_enc_kernel(
    const float* __restrict__ inw, const float* __restrict__ opw,
    const float* __restrict__ xpw, const float* __restrict__ dtw,
    ushort* __restrict__ inw_bf, ushort* __restrict__ opw_bf,
    ushort* __restrict__ comb_bf,
    const float* __restrict__ x, const float* __restrict__ encw,
    const float* __restrict__ encb, ushort* __restrict__ hbf)
{
    int tid = threadIdx.x;
    if (blockIdx.x < PREP_BLOCKS) {
        int i = blockIdx.x * 256 + tid;
        if (i < PREP_N1) {
            inw_bf[i] = f2bf(inw[i]);
            return;
        }
        int j = i - PREP_N1;
        if (j < PREP_N2) {
            opw_bf[j] = f2bf(opw[j]);
            return;
        }
        int m = j - PREP_N2;
        if (m >= PREP_N3) return;
        int l = m / (640 * 512);
        int rem = m - l * 640 * 512;
        int row = rem >> 9, k = rem & 511;
        const float* xp = xpw + l * 48 * 512;
        const float* dw = dtw + l * 512 * 16;
        float v;
        if (row < 512) {
            v = 0.f;
            #pragma unroll
            for (int r = 0; r < 16; ++r)
                v = fmaf(dw[row * 16 + r], xp[r * 512 + k], v);
        } else if (row < 544) {
            v = xp[(row - 512 + 16) * 512 + k];
        } else v = 0.f;
        comb_bf[m] = f2bf(v);
        return;
    }
    // ---- encoder branch ----
    __shared__ float sw[256 * 33];
    __shared__ float sx[4][32];
    for (int i = tid; i < 256 * 8; i += 256) {
        float4 v = ((const float4*)encw)[i];
        int r = i >> 3, c = (i & 7) * 4;
        sw[r * 33 + c + 0] = v.x; sw[r * 33 + c + 1] = v.y;
        sw[r * 33 + c + 2] = v.z; sw[r * 33 + c + 3] = v.w;
    }
    int row0 = (blockIdx.x - PREP_BLOCKS) * 4;
    if (tid < 32) {
        for (int rr = 0; rr < 4; ++rr)
            sx[rr][tid] = x[(size_t)(row0 + rr) * 32 + tid];
    }
    __syncthreads();
    float bb = encb[tid];
    #pragma unroll
    for (int rr = 0; rr < 4; ++rr) {
        float acc = bb;
        #pragma unroll
        for (int k = 0; k < 32; ++k)
            acc = fmaf(sx[rr][k], sw[tid * 33 + k], acc);
        hbf[(size_t)(row0 + rr) * DM + tid] = f2bf(acc);
    }
}

// ---------------- bf16 MFMA GEMM: C = epi(A @ W^T) -------------------------
// Tile 64(M) x 128(N), 4 waves of 32x64, single-buffered 24 KB LDS
// (m97-style 2-barrier k-loop; latency hidden by co-resident blocks).
// FINAL CONFIG — bracketing complete. Post-mortems:
//  R2:  128x128 -> 64x128 : WIN (+31 us) — more blocks/CU.
//  R12: 64x128 -> 32x128  : LOSS (-5 us) — full occupancy but half
//       MFMA-per-barrier; 64x128 is the optimum of this template.
//  R3: explicit LDS double-buffer (48 KB) -> -31 us (residency 6->3).
//  R5: forced launch_bounds(256,6) -> spill, flat despite traffic cuts.
//  R7: LDS-free direct fragment loads -> 2x SLOWER (each wave load touches
//      16 cache lines; LDS staging IS the coalescing transform here).
//  R9-R11: rank-16 xproj factorization -> net +11 us vs fused; reverted.
// EPI: 0 plain bf16 out; 1 combined-xproj (dt softplus->bf16, B/C->f32 bc);
//      2 residual bf16 read-modify-write on Cbf.
template<int EPI>
__global__ __launch_bounds__(256, 4) void mfma_gemm(
    const ushort* __restrict__ A, int lda,
    const ushort* __restrict__ W,
    const float* __restrict__ bias,
    float* __restrict__ C, int ldc,
    ushort* Cbf, int ldcbf,
    int K)
{
    __shared__ ushort As[64 * 64];
    __shared__ ushort Ws[128 * 64];
    const int tid = threadIdx.x;

    // XCD-aware bijective swizzle (nwg % 8 == 0 for all our launches)
    int nwg = gridDim.x * gridDim.y;
    int wlin = blockIdx.y * gridDim.x + blockIdx.x;
    int gx = blockIdx.x, gy = blockIdx.y;
    if ((nwg & 7) == 0) {
        int q = nwg >> 3;
        int s = (wlin & 7) * q + (wlin >> 3);
        gx = s % gridDim.x;
        gy = s / gridDim.x;
    }
    const int bm = gy * 64;
    const int bn = gx * 128;
    const int wid = tid >> 6, lane = tid & 63;
    const int wrow = (wid >> 1) * 32, wcol = (wid & 1) * 64;
    const int sr = tid >> 3;
    const int sc = tid & 7;

    f32x4 acc[2][4];
    #pragma unroll
    for (int mi = 0; mi < 2; ++mi)
        #pragma unroll
        for (int ni = 0; ni < 4; ++ni)
            acc[mi][ni] = (f32x4){0.f, 0.f, 0.f, 0.f};

    const int nk = K >> 6;          // 4 (K=256) or 8 (K=512)
    for (int t = 0; t < nk; ++t) {
        const int k0 = t << 6;
        #pragma unroll
        for (int it = 0; it < 2; ++it) {
            int r = it * 32 + sr;
            int csrc = sc ^ (r & 7);
            __builtin_amdgcn_global_load_lds(
                (const __attribute__((address_space(1))) unsigned int*)
                    (A + (size_t)(bm + r) * lda + k0 + csrc * 8),
                (__attribute__((address_space(3))) unsigned int*)
                    (As + r * 64 + sc * 8), 16, 0, 0);
        }
        #pragma unroll
        for (int it = 0; it < 4; ++it) {
            int r = it * 32 + sr;
            int csrc = sc ^ (r & 7);
            __builtin_amdgcn_global_load_lds(
                (const __attribute__((address_space(1))) unsigned int*)
                    (W + (size_t)(bn + r) * K + k0 + csrc * 8),
                (__attribute__((address_space(3))) unsigned int*)
                    (Ws + r * 64 + sc * 8), 16, 0, 0);
        }
        __syncthreads();
        #pragma unroll
        for (int kk = 0; kk < 2; ++kk) {
            short8 af[2], bfr[4];
            #pragma unroll
            for (int mi = 0; mi < 2; ++mi) {
                int r = wrow + mi * 16 + (lane & 15);
                int c = (lane >> 4) + kk * 4;
                af[mi] = *(const short8*)(As + r * 64 + ((c ^ (r & 7)) << 3));
            }
            #pragma unroll
            for (int ni = 0; ni < 4; ++ni) {
                int r = wcol + ni * 16 + (lane & 15);
                int c = (lane >> 4) + kk * 4;
                bfr[ni] = *(const short8*)(Ws + r * 64 + ((c ^ (r & 7)) << 3));
            }
            #pragma unroll
            for (int mi = 0; mi < 2; ++mi)
                #pragma unroll
                for (int ni = 0; ni < 4; ++ni)
                    acc[mi][ni] = __builtin_amdgcn_mfma_f32_16x16x32_bf16(
                        af[mi], bfr[ni], acc[mi][ni], 0, 0, 0);
        }
        __syncthreads();
    }

    #pragma unroll
    for (int mi = 0; mi < 2; ++mi)
        #pragma unroll
        for (int ni = 0; ni < 4; ++ni) {
            int col = bn + wcol + ni * 16 + (lane & 15);
            #pragma unroll
            for (int r = 0; r < 4; ++r) {
                int row = bm + wrow + mi * 16 + (lane >> 4) * 4 + r;
                float v = acc[mi][ni][r];
                if (EPI == 1) {
                    if (col < 512) {
                        float u = v + bias[col];
                        float sp = fmaxf(u, 0.f) + __logf(1.f + __expf(-fabsf(u)));
                        Cbf[(size_t)row * ldcbf + col] = f2bf(sp);
                    } else if (col < 544) {
                        C[(size_t)row * ldc + (col - 512)] = v;
                    }
                } else if (EPI == 2) {
                    size_t o = (size_t)row * ldcbf + col;
                    float vv = v + bf2f(Cbf[o]);
                    Cbf[o] = f2bf(vv);
                } else {
                    Cbf[(size_t)row * ldcbf + col] = f2bf(v);
                }
            }
        }
}

// ---------------- causal conv (width 4) + bias + silu, bf16 in/out ---------
// 16B/lane (ushort8): each thread walks 8 timesteps for 8 channels.
__global__ __launch_bounds__(256) void conv_silu_kernel(
    const ushort* __restrict__ xz, const float* __restrict__ cw,
    const float* __restrict__ cb, ushort* __restrict__ xi)
{
    int idx = blockIdx.x * 256 + threadIdx.x;   // over (BL/8)*64
    int d8 = (idx & 63) * 8;
    int grp = idx >> 6;                          // 0 .. BL/8-1
    int b = grp >> 9;                            // LL/8 = 512 groups per b
    int t0 = (grp & 511) * 8;
    const ushort* base = xz + ((size_t)(b * LL + t0) * 1024) + d8;
    ushort* obase = xi + ((size_t)(b * LL + t0) * 512) + d8;

    float wv[8][4];
    float bv[8];
    #pragma unroll
    for (int j = 0; j < 8; ++j) {
        float4 w = *(const float4*)(cw + (d8 + j) * 4);
        wv[j][0] = w.x; wv[j][1] = w.y; wv[j][2] = w.z; wv[j][3] = w.w;
        bv[j] = cb[d8 + j];
    }

    ushort8 z8 = {0,0,0,0,0,0,0,0};
    ushort8 win0 = (t0 >= 3) ? *(const ushort8*)(base - 3 * 1024) : z8;
    ushort8 win1 = (t0 >= 2) ? *(const ushort8*)(base - 2 * 1024) : z8;
    ushort8 win2 = (t0 >= 1) ? *(const ushort8*)(base - 1 * 1024) : z8;

    #pragma unroll
    for (int k = 0; k < 8; ++k) {
        ushort8 cur = *(const ushort8*)(base + k * 1024);
        ushort8 o;
        #pragma unroll
        for (int j = 0; j < 8; ++j) {
            float a = bv[j];
            a = fmaf(bf2f(win0[j]), wv[j][0], a);
            a = fmaf(bf2f(win1[j]), wv[j][1], a);
            a = fmaf(bf2f(win2[j]), wv[j][2], a);
            a = fmaf(bf2f(cur[j]),  wv[j][3], a);
            o[j] = f2bf(a / (1.f + __expf(-a)));
        }
        *(ushort8*)(obase + k * 512) = o;
        win0 = win1; win1 = win2; win2 = cur;
    }
}

// ---------------- chunked selective scan -----------------------------------
__global__ __launch_bounds__(256) void scan_phase1(
    const ushort* __restrict__ xi, const ushort* __restrict__ dtb,
    const float* __restrict__ bc,
    const float* __restrict__ alog,
    float* __restrict__ cS, float* __restrict__ cH)
{
    int d = blockIdx.z * 256 + threadIdx.x;
    int b = blockIdx.y, c = blockIdx.x;
    float Av[16];
    bool fast = true;
    #pragma unroll
    for (int s = 0; s < 16; ++s) {
        Av[s] = -__expf(alog[d * 16 + s]);
        fast = fast && (fabsf(Av[s] + (float)(s + 1)) < 1e-3f * (s + 1));
    }
    float h[16];
    #pragma unroll
    for (int s = 0; s < 16; ++s) h[s] = 0.f;
    float S = 0.f;
    int t0 = c * CLEN;
    if (fast) {
        for (int t = t0; t < t0 + CLEN; ++t) {
            size_t row = (size_t)b * LL + t;
            float dt = bf2f(dtb[row * 512 + d]);
            float x = bf2f(xi[row * 512 + d]);
            float dtx = dt * x;
            S += dt;
            const float* bp = bc + row * 32;
            float e1 = __expf(-dt);
            float e2=e1*e1, e3=e2*e1, e4=e2*e2, e5=e3*e2, e6=e3*e3, e7=e4*e3, e8=e4*e4;
            float e9=e5*e4, e10=e5*e5, e11=e6*e5, e12=e6*e6, e13=e7*e6, e14=e7*e7, e15=e8*e7, e16=e8*e8;
            float pw[16] = {e1,e2,e3,e4,e5,e6,e7,e8,e9,e10,e11,e12,e13,e14,e15,e16};
            #pragma unroll
            for (int s = 0; s < 16; ++s)
                h[s] = fmaf(pw[s], h[s], dtx * bp[s]);
        }
    } else {
        for (int t = t0; t < t0 + CLEN; ++t) {
            size_t row = (size_t)b * LL + t;
            float dt = bf2f(dtb[row * 512 + d]);
            float x = bf2f(xi[row * 512 + d]);
            float dtx = dt * x;
            S += dt;
            const float* bp = bc + row * 32;
            #pragma unroll
            for (int s = 0; s < 16; ++s) {
                float dA = __expf(dt * Av[s]);
                h[s] = fmaf(dA, h[s], dtx * bp[s]);
            }
        }
    }
    cS[((size_t)b * DI + d) * NC + c] = S;
    size_t base = (((size_t)b * DI + d) * NC + c) * 16;
    #pragma unroll
    for (int q = 0; q < 4; ++q)
        *(float4*)(cH + base + q*4) = *(float4*)&h[q*4];
}

// Parallel chunk-prefix: one block per (b,d); 16 threads per s-value,
// each composing 8 chunks; shfl-scan of affine maps F(x)=Ax+H across the
// 16-lane segment (serial chain 128 -> 8+4+8). Decay a = exp(Av[s]*S).
__global__ __launch_bounds__(256) void scan_phase2(
    const float* __restrict__ cS, float* __restrict__ cH,
    const float* __restrict__ alog)
{
    int bd = blockIdx.x;            // b*DI + d
    int d = bd & (DI - 1);
    int tid = threadIdx.x;
    int s = tid >> 4;               // 0..15
    int g = tid & 15;               // chunk group (8 chunks each)
    float Avs = -__expf(alog[d * 16 + s]);
    size_t sbase = (size_t)bd * NC;
    size_t base = (size_t)bd * NC * 16 + s;
    float a8[8], h8[8];
    #pragma unroll
    for (int j = 0; j < 8; ++j) {
        float Sj = cS[sbase + g * 8 + j];
        a8[j] = __expf(Avs * Sj);
        h8[j] = cH[base + (size_t)(g * 8 + j) * 16];
    }
    float A = 1.f, H = 0.f;
    #pragma unroll
    for (int j = 0; j < 8; ++j) {
        H = fmaf(a8[j], H, h8[j]);
        A *= a8[j];
    }
    #pragma unroll
    for (int off = 1; off < 16; off <<= 1) {
        float Ap = __shfl_up(A, off, 16);
        float Hp = __shfl_up(H, off, 16);
        if (g >= off) { H = fmaf(A, Hp, H); A *= Ap; }
    }
    float init = __shfl_up(H, 1, 16);
    if (g == 0) init = 0.f;
    #pragma unroll
    for (int j = 0; j < 8; ++j) {
        size_t o = base + (size_t)(g * 8 + j) * 16;
        cH[o] = init;
        init = fmaf(a8[j], init, h8[j]);
    }
}

__global__ __launch_bounds__(256) void scan_phase3(
    const ushort* __restrict__ xz,   // bf16, ld 1024; res at cols 512..1023
    ushort* __restrict__ xi,
    const ushort* __restrict__ dtb,
    const float* __restrict__ bc,
    const float* __restrict__ alog,
    const float* __restrict__ Dp,
    const float* __restrict__ cH,
    int c0)
{
    int d = blockIdx.z * 256 + threadIdx.x;
    int b = blockIdx.y;
    int c = blockIdx.x + c0;
    float Av[16];
    bool fast = true;
    #pragma unroll
    for (int s = 0; s < 16; ++s) {
        Av[s] = -__expf(alog[d * 16 + s]);
        fast = fast && (fabsf(Av[s] + (float)(s + 1)) < 1e-3f * (s + 1));
    }
    float h[16];
    size_t cbase = (((size_t)b * DI + d) * NC + c) * 16;
    #pragma unroll
    for (int q = 0; q < 4; ++q)
        *(float4*)&h[q*4] = *(const float4*)(cH + cbase + q*4);
    float Dd = Dp[d];
    int t0 = c * CLEN;
    if (fast) {
        for (int t = t0; t < t0 + CLEN; ++t) {
            size_t row = (size_t)b * LL + t;
            float dt = bf2f(dtb[row * 512 + d]);
            float x = bf2f(xi[row * 512 + d]);
            float dtx = dt * x;
            const float* bp = bc + row * 32;
            const float* cp = bc + row * 32 + 16;
            float e1 = __expf(-dt);
            float e2=e1*e1, e3=e2*e1, e4=e2*e2, e5=e3*e2, e6=e3*e3, e7=e4*e3, e8=e4*e4;
            float e9=e5*e4, e10=e5*e5, e11=e6*e5, e12=e6*e6, e13=e7*e6, e14=e7*e7, e15=e8*e7, e16=e8*e8;
            float pw[16] = {e1,e2,e3,e4,e5,e6,e7,e8,e9,e10,e11,e12,e13,e14,e15,e16};
            float y = 0.f;
            #pragma unroll
            for (int s = 0; s < 16; ++s) {
                h[s] = fmaf(pw[s], h[s], dtx * bp[s]);
                y = fmaf(h[s], cp[s], y);
            }
            float res = bf2f(xz[row * 1024 + 512 + d]);
            float g = (y + x * Dd) * (res / (1.f + __expf(-res)));
            xi[row * 512 + d] = f2bf(g);
        }
    } else {
        for (int t = t0; t < t0 + CLEN; ++t) {
            size_t row = (size_t)b * LL + t;
            float dt = bf2f(dtb[row * 512 + d]);
            float x = bf2f(xi[row * 512 + d]);
            float dtx = dt * x;
            const float* bp = bc + row * 32;
            const float* cp = bc + row * 32 + 16;
            float y = 0.f;
            #pragma unroll
            for (int s = 0; s < 16; ++s) {
                float dA = __expf(dt * Av[s]);
                h[s] = fmaf(dA, h[s], dtx * bp[s]);
                y = fmaf(h[s], cp[s], y);
            }
            float res = bf2f(xz[row * 1024 + 512 + d]);
            float g = (y + x * Dd) * (res / (1.f + __expf(-res)));
            xi[row * 512 + d] = f2bf(g);
        }
    }
}

// ---------------- fused tail: out_proj(last row) + residual + LN + head ----
// Grid BB x 256. Replaces out_proj_last_kernel + ln_head_kernel (one launch,
// hlast passes through registers instead of a global round-trip).
__global__ __launch_bounds__(256) void tail_kernel(
    const ushort* __restrict__ xi, const float* __restrict__ W,
    const ushort* __restrict__ hbf,
    const float* __restrict__ lng, const float* __restrict__ lnb,
    const float* __restrict__ hw, const float* __restrict__ hb,
    float* __restrict__ out)
{
    int b = blockIdx.x, tid = threadIdx.x;
    __shared__ float sy[DI];
    __shared__ float sh[DM];
    __shared__ float r1[4], r2[4];
    const ushort* yrow = xi + ((size_t)b * LL + (LL - 1)) * DI;
    for (int k = tid; k < DI; k += 256) sy[k] = bf2f(yrow[k]);
    __syncthreads();
    const float* wr = W + (size_t)tid * DI;
    float acc = 0.f;
    for (int k = 0; k < DI; k += 4) {
        float4 wv = *(const float4*)(wr + k);
        acc = fmaf(sy[k+0], wv.x, acc);
        acc = fmaf(sy[k+1], wv.y, acc);
        acc = fmaf(sy[k+2], wv.z, acc);
        acc = fmaf(sy[k+3], wv.w, acc);
    }
    float v = acc + bf2f(hbf[((size_t)b * LL + (LL - 1)) * DM + tid]);

    float s = v;
    #pragma unroll
    for (int o = 32; o >= 1; o >>= 1) s += __shfl_down(s, o);
    if ((tid & 63) == 0) r1[tid >> 6] = s;
    __syncthreads();
    float mu = (r1[0] + r1[1] + r1[2] + r1[3]) * (1.f / 256.f);
    float dv = v - mu;
    float q = dv * dv;
    #pragma unroll
    for (int o = 32; o >= 1; o >>= 1) q += __shfl_down(q, o);
    if ((tid & 63) == 0) r2[tid >> 6] = q;
    __syncthreads();
    float var = (r2[0] + r2[1] + r2[2] + r2[3]) * (1.f / 256.f);
    sh[tid] = dv * rsqrtf(var + LN_EPS) * lng[tid] + lnb[tid];
    __syncthreads();
    if (tid < NOUTK) {
        const float* hr = hw + (size_t)tid * DM;
        float a2 = hb[tid];
        for (int d2 = 0; d2 < DM; d2 += 4) {
            float4 wv = *(const float4*)(hr + d2);
            a2 = fmaf(sh[d2+0], wv.x, a2);
            a2 = fmaf(sh[d2+1], wv.y, a2);
            a2 = fmaf(sh[d2+2], wv.z, a2);
            a2 = fmaf(sh[d2+3], wv.w, a2);
        }
        out[b * NOUTK + tid] = a2;
    }
}

extern "C" void kernel_launch(void* const* d_in, const int* in_sizes, int n_in,
                              void* d_out, int out_size, void* d_ws, size_t ws_size,
                              hipStream_t stream)
{
    const float* x    = (const float*)d_in[0];
    const float* encw = (const float*)d_in[1];
    const float* encb = (const float*)d_in[2];
    const float* inw  = (const float*)d_in[3];
    const float* cw   = (const float*)d_in[4];
    const float* cb   = (const float*)d_in[5];
    const float* xpw  = (const float*)d_in[6];
    const float* dtw  = (const float*)d_in[7];
    const float* dtb  = (const float*)d_in[8];
    const float* alog = (const float*)d_in[9];
    const float* Dp   = (const float*)d_in[10];
    const float* opw  = (const float*)d_in[11];
    const float* lng  = (const float*)d_in[12];
    const float* lnb  = (const float*)d_in[13];
    const float* hw   = (const float*)d_in[14];
    const float* hb   = (const float*)d_in[15];
    float* out = (float*)d_out;

    float* ws   = (float*)d_ws;
    float* bc   = ws;                               // BL*32 f32 (B|C)
    float* cS   = bc  + (size_t)BL * 32;            // B*DI*NC f32 (sum dt)
    float* cH   = cS  + (size_t)BB * DI * NC;       // B*DI*NC*16 f32
    ushort* h_bf    = (ushort*)(cH + (size_t)BB * DI * NC * DS);  // BL*256
    ushort* xz_bf   = h_bf  + (size_t)BL * DM;      // BL*1024
    ushort* xi_bf   = xz_bf + (size_t)BL * 1024;    // BL*512
    ushort* dt_bf   = xi_bf + (size_t)BL * DI;      // BL*512 (softplus'd dt)
    ushort* inw_bf  = dt_bf + (size_t)BL * DI;      // 2*1024*256
    ushort* opw_bf  = inw_bf + 2 * 1024 * DM;       // 2*256*512
    ushort* comb_bf = opw_bf + 2 * DM * DI;         // 2*640*512

    dim3 blk(256, 1, 1);

    prep_enc_kernel<<<dim3(PREP_BLOCKS + ENC_BLOCKS), blk, 0, stream>>>(
        inw, opw, xpw, dtw, inw_bf, opw_bf, comb_bf,
        x, encw, encb, h_bf);

    for (int l = 0; l < 2; ++l) {
        // in_proj -> xz_bf (bf16 only)
        mfma_gemm<0><<<dim3(1024/128, BL/64), blk, 0, stream>>>(
            h_bf, DM, inw_bf + (size_t)l * 1024 * DM, nullptr,
            nullptr, 0, xz_bf, 1024, DM);
        // conv + silu -> xi_bf
        conv_silu_kernel<<<dim3(BL * 64 / 8 / 256), blk, 0, stream>>>(
            xz_bf, cw + l * DI * 4, cb + l * DI, xi_bf);
        // combined xproj+dtproj: dt_bf = bf16(softplus(xi@Wdt^T + dtb)),
        // bc = f32 [B|C]
        mfma_gemm<1><<<dim3(LDB/128, BL/64), blk, 0, stream>>>(
            xi_bf, DI, comb_bf + (size_t)l * LDB * DI, dtb + l * DI,
            bc, 32, dt_bf, 512, DI);
        // scan
        scan_phase1<<<dim3(NC, BB, 2), blk, 0, stream>>>(
            xi_bf, dt_bf, bc, alog + (size_t)l * DI * 16, cS, cH);
        scan_phase2<<<dim3(BB * DI), blk, 0, stream>>>(
            cS, cH, alog + (size_t)l * DI * 16);
        if (l == 0) {
            scan_phase3<<<dim3(NC, BB, 2), blk, 0, stream>>>(
                xz_bf, xi_bf, dt_bf, bc, alog + (size_t)l * DI * 16,
                Dp + l * DI, cH, 0);
            // out_proj with bf16 residual read-modify-write on h_bf
            mfma_gemm<2><<<dim3(DM/128, BL/64), blk, 0, stream>>>(
                xi_bf, DI, opw_bf + (size_t)l * DM * DI, nullptr,
                nullptr, 0, h_bf, DM, DI);
        } else {
            scan_phase3<<<dim3(1, BB, 2), blk, 0, stream>>>(
                xz_bf, xi_bf, dt_bf, bc, alog + (size_t)l * DI * 16,
                Dp + l * DI, cH, NC - 1);
            tail_kernel<<<dim3(BB), blk, 0, stream>>>(
                xi_bf, opw + (size_t)l * DM * DI, h_bf,
                lng, lnb, hw, hb, out);
        }
    }
}